// Round 10
// baseline (591.610 us; speedup 1.0000x reference)
//
#include <hip/hip_runtime.h>

typedef float f4 __attribute__((ext_vector_type(4)));
typedef float f32x4 __attribute__((ext_vector_type(4)));
typedef float f2 __attribute__((ext_vector_type(2)));
typedef short s16x8 __attribute__((ext_vector_type(8)));
typedef int i4 __attribute__((ext_vector_type(4)));

#define N_NODES 100000
#define NBUCK 196   // ceil(100000/512)
#define NB1 256     // blocks in hist/place passes

__device__ inline unsigned short f2bf(float f) {
    unsigned int u = __builtin_bit_cast(unsigned int, f);
    u += 0x7FFFu + ((u >> 16) & 1u);
    return (unsigned short)(u >> 16);
}
__device__ inline float bflo(unsigned int v) { return __builtin_bit_cast(float, v << 16); }
__device__ inline float bfhi(unsigned int v) { return __builtin_bit_cast(float, v & 0xFFFF0000u); }

// async global->LDS, 16B per lane; LDS dest is wave-uniform base + lane*16
#define GLDS(gp, lp)                                                            \
    __builtin_amdgcn_global_load_lds(                                           \
        (const __attribute__((address_space(1))) void*)(gp),                    \
        (__attribute__((address_space(3))) void*)(lp), 16, 0, 0)

// accumulate 4 dwords (8 bf16) into 4 f2 accumulators
__device__ inline void acc8(f2& a0, f2& a1, f2& a2, f2& a3, i4 u) {
    f2 t0 = {bflo((unsigned int)u[0]), bfhi((unsigned int)u[0])};
    f2 t1 = {bflo((unsigned int)u[1]), bfhi((unsigned int)u[1])};
    f2 t2 = {bflo((unsigned int)u[2]), bfhi((unsigned int)u[2])};
    f2 t3 = {bflo((unsigned int)u[3]), bfhi((unsigned int)u[3])};
    a0 += t0; a1 += t1; a2 += t2; a3 += t3;
}

// ---------------- bucketed CSR build ----------------
// bucket = dst >> 9 (512 nodes per bucket); edge packed as src | (dst&511)<<17

__global__ __launch_bounds__(256) void k_hist(const int* __restrict__ dst,
                                              int* __restrict__ histG, int E) {
    __shared__ int h[NBUCK];
    int tid = threadIdx.x;
    for (int i = tid; i < NBUCK; i += 256) h[i] = 0;
    __syncthreads();
    int chunk = (E + NB1 - 1) / NB1;
    int s = blockIdx.x * chunk, eN = min(E, s + chunk);
    for (int i = s + tid; i < eN; i += 256) atomicAdd(&h[dst[i] >> 9], 1);
    __syncthreads();
    for (int i = tid; i < NBUCK; i += 256) histG[i * NB1 + blockIdx.x] = h[i];
}

__global__ __launch_bounds__(1024) void k_scanB(int* __restrict__ histG) {
    __shared__ int ps[1024];
    int t = threadIdx.x;
    int base = t * 49;
    int vals[49];
    int sum = 0;
#pragma unroll
    for (int i = 0; i < 49; ++i) { vals[i] = histG[base + i]; sum += vals[i]; }
    ps[t] = sum;
    __syncthreads();
    for (int off = 1; off < 1024; off <<= 1) {
        int v = (t >= off) ? ps[t - off] : 0;
        __syncthreads();
        ps[t] += v;
        __syncthreads();
    }
    int run = ps[t] - sum;
#pragma unroll
    for (int i = 0; i < 49; ++i) { int v = vals[i]; histG[base + i] = run; run += v; }
}

__global__ __launch_bounds__(256) void k_place(const int* __restrict__ src,
                                               const int* __restrict__ dst,
                                               const int* __restrict__ histG,
                                               unsigned int* __restrict__ ebuf, int E) {
    __shared__ int cur[NBUCK];
    int tid = threadIdx.x;
    for (int i = tid; i < NBUCK; i += 256) cur[i] = histG[i * NB1 + blockIdx.x];
    __syncthreads();
    int chunk = (E + NB1 - 1) / NB1;
    int s = blockIdx.x * chunk, eN = min(E, s + chunk);
    for (int i = s + tid; i < eN; i += 256) {
        int d = dst[i];
        int b = d >> 9;
        int pos = atomicAdd(&cur[b], 1);
        ebuf[pos] = (unsigned int)src[i] | ((unsigned int)(d & 511) << 17);
    }
}

// one block per bucket: LDS degree count + scan, then L2-local col scatter.
// col is stored as BYTE offsets (src*256) for the bf16 row gather.
__global__ __launch_bounds__(256) void k_csr(const unsigned int* __restrict__ ebuf,
                                             const int* __restrict__ histG,
                                             int* __restrict__ rp, int* __restrict__ col,
                                             float* __restrict__ invd, int N, int E) {
    __shared__ int ldeg[512];
    __shared__ int lbase[512];
    int b = blockIdx.x, tid = threadIdx.x;
    int base = histG[b * NB1];
    int endB = (b == NBUCK - 1) ? E : histG[(b + 1) * NB1];
    int cnt = endB - base;
    int n0 = b << 9;

    ldeg[tid] = 0;
    ldeg[tid + 256] = 0;
    __syncthreads();
    for (int i = tid; i < cnt; i += 256) atomicAdd(&ldeg[ebuf[base + i] >> 17], 1);
    __syncthreads();

    int a0 = ldeg[tid], a1 = ldeg[tid + 256];
    lbase[tid] = a0;
    lbase[tid + 256] = a1;
    __syncthreads();
    for (int off = 1; off < 512; off <<= 1) {
        int v0 = (tid >= off) ? lbase[tid - off] : 0;
        int v1 = (tid + 256 >= off) ? lbase[tid + 256 - off] : 0;
        __syncthreads();
        lbase[tid] += v0;
        lbase[tid + 256] += v1;
        __syncthreads();
    }
    int e0 = lbase[tid] - a0, e1 = lbase[tid + 256] - a1;
    __syncthreads();
    lbase[tid] = e0;
    lbase[tid + 256] = e1;
    ldeg[tid] = 0;
    ldeg[tid + 256] = 0;
    __syncthreads();

    for (int i = tid; i < cnt; i += 256) {
        unsigned int p = ebuf[base + i];
        int dl = p >> 17;
        int pos = base + lbase[dl] + atomicAdd(&ldeg[dl], 1);
        col[pos] = (int)(p & 0x1FFFFu) << 8;   // byte offset into 256B bf16 rows
    }

    int g0 = n0 + tid, g1 = n0 + tid + 256;
    if (g0 < N) { rp[g0] = base + e0; invd[g0] = 1.0f / fmaxf((float)a0, 1.0f); }
    if (g1 < N) { rp[g1] = base + e1; invd[g1] = 1.0f / fmaxf((float)a1, 1.0f); }
    if (b == NBUCK - 1 && tid == 0) rp[N] = E;
    if (b == NBUCK - 1 && tid < 32) col[E + tid] = 0;   // slack for tail over-read
}

// ---------------- prep: f32 -> bf16 conversions / weight packing ----------------

__global__ void k_cvt(const float* __restrict__ x, unsigned short* __restrict__ xb, int n8) {
    int t = blockIdx.x * 256 + threadIdx.x;
    if (t >= n8) return;
    f4 a = *(const f4*)&x[(size_t)t * 8];
    f4 b = *(const f4*)&x[(size_t)t * 8 + 4];
    s16x8 p;
    p[0] = (short)f2bf(a[0]); p[1] = (short)f2bf(a[1]);
    p[2] = (short)f2bf(a[2]); p[3] = (short)f2bf(a[3]);
    p[4] = (short)f2bf(b[0]); p[5] = (short)f2bf(b[1]);
    p[6] = (short)f2bf(b[2]); p[7] = (short)f2bf(b[3]);
    *(s16x8*)&xb[(size_t)t * 8] = p;
}

// pack W^T fragments: wp[layer][ks(8)][nfg(8)][lane(64)][8]; k<128 -> ws, else wn
__global__ void k_prepw(const float* __restrict__ ws, const float* __restrict__ wn,
                        unsigned short* __restrict__ wp) {
    int t = blockIdx.x * 256 + threadIdx.x;
    if (t >= 5 * 4096) return;
    int l = t & 63, nfg = (t >> 6) & 7, ks = (t >> 9) & 7, lyr = t >> 12;
    int n = nfg * 16 + (l & 15);
    s16x8 p;
#pragma unroll
    for (int j = 0; j < 8; ++j) {
        int k = ks * 32 + (l >> 4) * 8 + j;
        float v = (k < 128) ? ws[((size_t)lyr * 128 + k) * 128 + n]
                            : wn[((size_t)lyr * 128 + (k - 128)) * 128 + n];
        p[j] = (short)f2bf(v);
    }
    *(s16x8*)&wp[(size_t)t * 8] = p;
}

// pack output-layer W^T fragments, separate self/neigh tables (K=128 each):
// wS/wN[ks(4)][nf(3)][lane(64)][8], cols >=47 zero. Also bo48 (padded bias).
__global__ void k_prepwo(const float* __restrict__ wso, const float* __restrict__ wno,
                         unsigned short* __restrict__ wS, unsigned short* __restrict__ wN,
                         const float* __restrict__ bo, float* __restrict__ bo48) {
    int t = blockIdx.x * 256 + threadIdx.x;
    if (t < 48) bo48[t] = (t < 47) ? bo[t] : 0.f;
    if (t >= 2 * 768) return;
    int tbl = t / 768, r = t % 768;
    int ks = r / 192, nf = (r / 64) % 3, l = r & 63;
    int n = nf * 16 + (l & 15);
    const float* W = tbl ? wno : wso;
    unsigned short* dstp = tbl ? wN : wS;
    s16x8 p;
#pragma unroll
    for (int j = 0; j < 8; ++j) {
        int k = ks * 32 + (l >> 4) * 8 + j;
        float v = (n < 47) ? W[(size_t)k * 47 + n] : 0.f;
        p[j] = (short)f2bf(v);
    }
    *(s16x8*)&dstp[(size_t)r * 8] = p;
}

// ---------------- mean aggregation, dwordx4 gather (4 edges per instruction) ---
// Lane i serves edge e + (i>>4), bytes (i&15)*16 .. +15 of that row.
// Epilogue: shfl_xor(16,32) reduce; lanes 0-15 write the 256B result row.

__global__ __launch_bounds__(256) void k_agg(const unsigned short* __restrict__ h,
                                             const int* __restrict__ rp,
                                             const int* __restrict__ col,
                                             const float* __restrict__ invd,
                                             unsigned short* __restrict__ out, int n) {
    int gw = (blockIdx.x * 256 + threadIdx.x) >> 6;
    int lane = threadIdx.x & 63;
    if (gw >= n) return;
    const char* hb = (const char*)h;
    const int sub = lane >> 4;          // edge slot within quad
    const int lb = (lane & 15) * 16;    // byte chunk within 256B row
    int beg = rp[gw], end = rp[gw + 1];
    f2 a0 = {0.f, 0.f}, a1 = {0.f, 0.f}, a2 = {0.f, 0.f}, a3 = {0.f, 0.f};
    int e = beg;
    for (; e + 8 <= end; e += 8) {
        unsigned int c0 = (unsigned int)col[e + sub];
        unsigned int c1 = (unsigned int)col[e + 4 + sub];
        i4 u, v;
        __builtin_memcpy(&u, hb + c0 + lb, 16);
        __builtin_memcpy(&v, hb + c1 + lb, 16);
        acc8(a0, a1, a2, a3, u);
        acc8(a0, a1, a2, a3, v);
    }
    if (e < end) {
        // masked tail (1..7 edges); col slack (>=32 zeros) keeps reads in-bounds
        unsigned int c0 = (unsigned int)col[e + sub];
        unsigned int c1 = (unsigned int)col[e + 4 + sub];
        i4 u, v;
        __builtin_memcpy(&u, hb + c0 + lb, 16);
        __builtin_memcpy(&v, hb + c1 + lb, 16);
        if (e + sub < end) acc8(a0, a1, a2, a3, u);
        if (e + 4 + sub < end) acc8(a0, a1, a2, a3, v);
    }
    // reduce the 4 edge-slots: lanes {i, i^16, i^32, i^48} hold the same chunk
#pragma unroll
    for (int off = 16; off <= 32; off <<= 1) {
        a0[0] += __shfl_xor(a0[0], off); a0[1] += __shfl_xor(a0[1], off);
        a1[0] += __shfl_xor(a1[0], off); a1[1] += __shfl_xor(a1[1], off);
        a2[0] += __shfl_xor(a2[0], off); a2[1] += __shfl_xor(a2[1], off);
        a3[0] += __shfl_xor(a3[0], off); a3[1] += __shfl_xor(a3[1], off);
    }
    if (lane < 16) {
        float iv = invd[gw];
        i4 r;
        r[0] = (int)((unsigned int)f2bf(a0[0] * iv) | ((unsigned int)f2bf(a0[1] * iv) << 16));
        r[1] = (int)((unsigned int)f2bf(a1[0] * iv) | ((unsigned int)f2bf(a1[1] * iv) << 16));
        r[2] = (int)((unsigned int)f2bf(a2[0] * iv) | ((unsigned int)f2bf(a2[1] * iv) << 16));
        r[3] = (int)((unsigned int)f2bf(a3[0] * iv) | ((unsigned int)f2bf(a3[1] * iv) << 16));
        *(i4*)((char*)out + (size_t)gw * 256 + lb) = r;
    }
}

// ---------------- fused dual MFMA GEMM (LDS-staged via global_load_lds) --------
// out = relu?(h@Ws + nb@Wn + b). 128-row tile, K=256 (h|nb), N=128. 4 waves.

__global__ __launch_bounds__(256) void gemm128(const unsigned short* __restrict__ h,
                                               const unsigned short* __restrict__ nb,
                                               const unsigned short* __restrict__ wl,
                                               const float* __restrict__ bias,
                                               unsigned short* __restrict__ out,
                                               int M, int relu) {
    __shared__ s16x8 afr[4096];  // [ks(8)][mf(8)][lane(64)] : 64 KB
    const int tid = threadIdx.x;
    const int l = tid & 63, w = tid >> 6;
    const int r0 = blockIdx.x * 128;
    const int cg = (w * 4 + (l >> 4)) * 8;

#pragma unroll
    for (int i = 0; i < 8; ++i) {
        int r = r0 + i * 16 + (l & 15);
        if (r >= M) r = M - 1;
        GLDS(h + (size_t)r * 128 + cg, &afr[(w * 8 + i) * 64]);
        GLDS(nb + (size_t)r * 128 + cg, &afr[((w + 4) * 8 + i) * 64]);
    }
    asm volatile("s_waitcnt vmcnt(0)");
    __syncthreads();

    const int mh = w >> 1, nh = w & 1;
    const s16x8* wf = (const s16x8*)wl;

    f32x4 acc[4][4];
#pragma unroll
    for (int i = 0; i < 4; ++i)
#pragma unroll
        for (int j = 0; j < 4; ++j) acc[i][j] = (f32x4)0.f;

#pragma unroll
    for (int ks = 0; ks < 8; ++ks) {
        s16x8 bw[4], ha[4];
#pragma unroll
        for (int nf = 0; nf < 4; ++nf) bw[nf] = wf[(ks * 8 + nh * 4 + nf) * 64 + l];
#pragma unroll
        for (int mf = 0; mf < 4; ++mf) ha[mf] = afr[(ks * 8 + mh * 4 + mf) * 64 + l];
#pragma unroll
        for (int mf = 0; mf < 4; ++mf)
#pragma unroll
            for (int nf = 0; nf < 4; ++nf)
                acc[mf][nf] = __builtin_amdgcn_mfma_f32_16x16x32_bf16(bw[nf], ha[mf],
                                                                      acc[mf][nf], 0, 0, 0);
    }

    f4 bv[4];
#pragma unroll
    for (int nf = 0; nf < 4; ++nf)
        bv[nf] = *(const f4*)&bias[nh * 64 + nf * 16 + ((l >> 4) << 2)];

#pragma unroll
    for (int mf = 0; mf < 4; ++mf) {
        int row = r0 + mh * 64 + mf * 16 + (l & 15);
        if (row >= M) continue;
#pragma unroll
        for (int nf = 0; nf < 4; ++nf) {
            int ncol = nh * 64 + nf * 16 + ((l >> 4) << 2);
            f32x4 a = acc[mf][nf];
            float v0 = a[0] + bv[nf][0], v1 = a[1] + bv[nf][1];
            float v2 = a[2] + bv[nf][2], v3 = a[3] + bv[nf][3];
            if (relu) {
                v0 = fmaxf(v0, 0.f); v1 = fmaxf(v1, 0.f);
                v2 = fmaxf(v2, 0.f); v3 = fmaxf(v3, 0.f);
            }
            uint2 p;
            p.x = (unsigned int)f2bf(v0) | ((unsigned int)f2bf(v1) << 16);
            p.y = (unsigned int)f2bf(v2) | ((unsigned int)f2bf(v3) << 16);
            *(uint2*)(out + (size_t)row * 128 + ncol) = p;
        }
    }
}

// ---------------- final layer, dense part: tmpn = h@wno (bf16), selfo = h@wso+bo
// Block = 64 rows, 4 waves (2 row-halves x {self, neigh}).

__global__ __launch_bounds__(256) void gemm_fin(const unsigned short* __restrict__ h,
                                                const unsigned short* __restrict__ wS,
                                                const unsigned short* __restrict__ wN,
                                                const float* __restrict__ bo48,
                                                unsigned short* __restrict__ tmpn,
                                                float* __restrict__ selfo, int M) {
    const int tid = threadIdx.x;
    const int l = tid & 63, wv = tid >> 6;
    const int mh = wv >> 1, sel = wv & 1;   // sel: 0 = self (f32+bias), 1 = neigh (bf16)
    const int r0 = blockIdx.x * 64;
    const s16x8* wf = (const s16x8*)(sel ? wN : wS);
    const int cgb = (l >> 4) << 3;

    int R[2];
#pragma unroll
    for (int mf = 0; mf < 2; ++mf) {
        int r = r0 + mh * 32 + mf * 16 + (l & 15);
        R[mf] = (r > M - 1) ? (M - 1) : r;
    }

    f32x4 acc[2][3];
#pragma unroll
    for (int i = 0; i < 2; ++i)
#pragma unroll
        for (int j = 0; j < 3; ++j) acc[i][j] = (f32x4)0.f;

#pragma unroll
    for (int ks = 0; ks < 4; ++ks) {
        s16x8 ha[2];
#pragma unroll
        for (int mf = 0; mf < 2; ++mf)
            ha[mf] = *(const s16x8*)(h + (size_t)R[mf] * 128 + ks * 32 + cgb);
#pragma unroll
        for (int nf = 0; nf < 3; ++nf) {
            s16x8 bw = wf[(ks * 3 + nf) * 64 + l];
            acc[0][nf] = __builtin_amdgcn_mfma_f32_16x16x32_bf16(bw, ha[0], acc[0][nf], 0, 0, 0);
            acc[1][nf] = __builtin_amdgcn_mfma_f32_16x16x32_bf16(bw, ha[1], acc[1][nf], 0, 0, 0);
        }
    }

#pragma unroll
    for (int mf = 0; mf < 2; ++mf) {
        int row = r0 + mh * 32 + mf * 16 + (l & 15);
        if (row >= M) continue;
#pragma unroll
        for (int nf = 0; nf < 3; ++nf) {
            int ncol = nf * 16 + ((l >> 4) << 2);
            f32x4 a = acc[mf][nf];
            if (sel == 0) {
                f4 bv = *(const f4*)&bo48[ncol];
                f4 o;
                o[0] = a[0] + bv[0]; o[1] = a[1] + bv[1];
                o[2] = a[2] + bv[2]; o[3] = a[3] + bv[3];
                *(f4*)&selfo[(size_t)row * 48 + ncol] = o;
            } else {
                uint2 p;
                p.x = (unsigned int)f2bf(a[0]) | ((unsigned int)f2bf(a[1]) << 16);
                p.y = (unsigned int)f2bf(a[2]) | ((unsigned int)f2bf(a[3]) << 16);
                *(uint2*)(tmpn + (size_t)row * 64 + ncol) = p;
            }
        }
    }
}

// ---------------- final aggregation, dwordx4 gather over 128B rows -------------
// 8 edges per instruction: lane i serves edge e + (i>>3), bytes (i&7)*16.

__global__ __launch_bounds__(256) void k_agg_fin(const unsigned short* __restrict__ z,
                                                 const float* __restrict__ selfo,
                                                 const int* __restrict__ rp,
                                                 const int* __restrict__ col,
                                                 const float* __restrict__ invd,
                                                 float* __restrict__ out, int n) {
    int gw = (blockIdx.x * 256 + threadIdx.x) >> 6;
    int lane = threadIdx.x & 63;
    if (gw >= n) return;
    const char* zb = (const char*)z;
    const int sub = lane >> 3;         // edge slot within octet
    const int lb = (lane & 7) * 16;    // byte chunk within 128B row
    int beg = rp[gw], end = rp[gw + 1];
    f2 a0 = {0.f, 0.f}, a1 = {0.f, 0.f}, a2 = {0.f, 0.f}, a3 = {0.f, 0.f};
    int e = beg;
    for (; e + 8 <= end; e += 8) {
        unsigned int c = (unsigned int)col[e + sub];   // src*256
        i4 u;
        __builtin_memcpy(&u, zb + (c >> 1) + lb, 16);
        acc8(a0, a1, a2, a3, u);
    }
    if (e < end) {
        unsigned int c = (unsigned int)col[e + sub];
        i4 u;
        __builtin_memcpy(&u, zb + (c >> 1) + lb, 16);
        if (e + sub < end) acc8(a0, a1, a2, a3, u);
    }
    // reduce the 8 edge-slots: xor 8, 16, 32
#pragma unroll
    for (int off = 8; off <= 32; off <<= 1) {
        a0[0] += __shfl_xor(a0[0], off); a0[1] += __shfl_xor(a0[1], off);
        a1[0] += __shfl_xor(a1[0], off); a1[1] += __shfl_xor(a1[1], off);
        a2[0] += __shfl_xor(a2[0], off); a2[1] += __shfl_xor(a2[1], off);
        a3[0] += __shfl_xor(a3[0], off); a3[1] += __shfl_xor(a3[1], off);
    }
    if (lane < 8) {
        float iv = invd[gw];
        int c0 = lane * 8;
        float o[8] = {a0[0], a0[1], a1[0], a1[1], a2[0], a2[1], a3[0], a3[1]};
#pragma unroll
        for (int j = 0; j < 8; ++j) {
            int c = c0 + j;
            if (c < 47)
                out[(size_t)gw * 47 + c] = selfo[(size_t)gw * 48 + c] + o[j] * iv;
        }
    }
}

// ---------------- launch ----------------

static inline char* alignp(char* p) {
    return (char*)(((size_t)p + 255) & ~(size_t)255);
}

extern "C" void kernel_launch(void* const* d_in, const int* in_sizes, int n_in,
                              void* d_out, int out_size, void* d_ws, size_t ws_size,
                              hipStream_t stream) {
    const float* x = (const float*)d_in[0];
    const int* src = (const int*)d_in[1];
    const int* dst = (const int*)d_in[2];
    const float* w_self = (const float*)d_in[3];
    const float* w_neigh = (const float*)d_in[4];
    const float* b = (const float*)d_in[5];
    const float* wso = (const float*)d_in[6];
    const float* wno = (const float*)d_in[7];
    const float* bo = (const float*)d_in[8];
    float* out = (float*)d_out;

    const int N = N_NODES;
    const int E = in_sizes[1];

    char* w = (char*)d_ws;
    unsigned short* xb = (unsigned short*)w;   w = alignp(w + (size_t)N * 128 * 2);
    unsigned short* hA = (unsigned short*)w;   w = alignp(w + (size_t)N * 128 * 2);
    unsigned short* hB = (unsigned short*)w;   w = alignp(w + (size_t)N * 128 * 2);
    unsigned short* nbuf = (unsigned short*)w; w = alignp(w + (size_t)N * 128 * 2);
    unsigned short* wp = (unsigned short*)w;   w = alignp(w + (size_t)5 * 32768 * 2);
    unsigned short* wS = (unsigned short*)w;   w = alignp(w + (size_t)768 * 8 * 2);
    unsigned short* wN = (unsigned short*)w;   w = alignp(w + (size_t)768 * 8 * 2);
    float* bo48 = (float*)w; w = alignp(w + 48 * 4);
    int* rp = (int*)w;       w = alignp(w + (size_t)(N + 4) * 4);
    int* col = (int*)w;      w = alignp(w + (size_t)(E + 32) * 4);
    int* histG = (int*)w;    w = alignp(w + (size_t)NBUCK * NB1 * 4);
    float* invd = (float*)w; w = alignp(w + (size_t)N * 4);

    // Aliases (lifetimes disjoint):
    // ebuf (packed edges) lives in hB: hB first written at layer-1 GEMM output.
    unsigned int* ebuf = (unsigned int*)hB;
    // final layer: tmpn (100K x 64 bf16) in nbuf; selfo (100K x 48 f32) in hB.
    unsigned short* tmpn = nbuf;

    // CSR build (bucketed, L2-local scatters)
    k_hist<<<NB1, 256, 0, stream>>>(dst, histG, E);
    k_scanB<<<1, 1024, 0, stream>>>(histG);
    k_place<<<NB1, 256, 0, stream>>>(src, dst, histG, ebuf, E);
    k_csr<<<NBUCK, 256, 0, stream>>>(ebuf, histG, rp, col, invd, N, E);

    // dtype prep
    k_cvt<<<(N * 128 / 8 + 255) / 256, 256, 0, stream>>>(x, xb, N * 128 / 8);
    k_prepw<<<(5 * 4096 + 255) / 256, 256, 0, stream>>>(w_self, w_neigh, wp);
    k_prepwo<<<6, 256, 0, stream>>>(wso, wno, wS, wN, bo, bo48);

    const int aggBlocks = (N * 64 + 255) / 256;   // 25000
    const int gemmBlocks = (N + 127) / 128;       // 782
    const int finBlocks = (N + 63) / 64;          // 1563

    // layer 0 (no relu): agg(xb)->nbuf, gemm -> hA
    k_agg<<<aggBlocks, 256, 0, stream>>>(xb, rp, col, invd, nbuf, N);
    gemm128<<<gemmBlocks, 256, 0, stream>>>(xb, nbuf, wp, b, hA, N, 0);

    unsigned short* cur = hA;
    unsigned short* oth = hB;
    for (int lyr = 1; lyr < 5; ++lyr) {
        k_agg<<<aggBlocks, 256, 0, stream>>>(cur, rp, col, invd, nbuf, N);
        gemm128<<<gemmBlocks, 256, 0, stream>>>(cur, nbuf, wp + (size_t)lyr * 32768,
                                                b + (size_t)lyr * 128, oth, N, 1);
        unsigned short* t = cur; cur = oth; oth = t;
    }
    // after L0..L4: cur == hA, oth == hB

    // final layer: dense transforms first, then 128B-row aggregation
    float* selfo = (float*)hB;
    gemm_fin<<<finBlocks, 256, 0, stream>>>(cur, wS, wN, bo48, tmpn, selfo, N);
    k_agg_fin<<<aggBlocks, 256, 0, stream>>>(tmpn, selfo, rp, col, invd, out, N);
}

// Round 11
// 561.424 us; speedup vs baseline: 1.0538x; 1.0538x over previous
//
#include <hip/hip_runtime.h>

typedef float f4 __attribute__((ext_vector_type(4)));
typedef float f32x4 __attribute__((ext_vector_type(4)));
typedef float f2 __attribute__((ext_vector_type(2)));
typedef short s16x8 __attribute__((ext_vector_type(8)));
typedef int i4 __attribute__((ext_vector_type(4)));

#define N_NODES 100000
#define NBUCK 196   // ceil(100000/512)
#define NB1 256     // blocks in hist/place passes

__device__ inline unsigned short f2bf(float f) {
    unsigned int u = __builtin_bit_cast(unsigned int, f);
    u += 0x7FFFu + ((u >> 16) & 1u);
    return (unsigned short)(u >> 16);
}
__device__ inline float bflo(unsigned int v) { return __builtin_bit_cast(float, v << 16); }
__device__ inline float bfhi(unsigned int v) { return __builtin_bit_cast(float, v & 0xFFFF0000u); }

// async global->LDS, 16B per lane; LDS dest is wave-uniform base + lane*16
#define GLDS(gp, lp)                                                            \
    __builtin_amdgcn_global_load_lds(                                           \
        (const __attribute__((address_space(1))) void*)(gp),                    \
        (__attribute__((address_space(3))) void*)(lp), 16, 0, 0)

// accumulate 4 dwords (8 bf16) into 4 f2 accumulators
__device__ inline void acc8(f2& a0, f2& a1, f2& a2, f2& a3, i4 u) {
    f2 t0 = {bflo((unsigned int)u[0]), bfhi((unsigned int)u[0])};
    f2 t1 = {bflo((unsigned int)u[1]), bfhi((unsigned int)u[1])};
    f2 t2 = {bflo((unsigned int)u[2]), bfhi((unsigned int)u[2])};
    f2 t3 = {bflo((unsigned int)u[3]), bfhi((unsigned int)u[3])};
    a0 += t0; a1 += t1; a2 += t2; a3 += t3;
}

// ---------------- bucketed CSR build ----------------
// bucket = dst >> 9 (512 nodes per bucket); edge packed as src | (dst&511)<<17

__global__ __launch_bounds__(256) void k_hist(const int* __restrict__ dst,
                                              int* __restrict__ histG, int E) {
    __shared__ int h[NBUCK];
    int tid = threadIdx.x;
    for (int i = tid; i < NBUCK; i += 256) h[i] = 0;
    __syncthreads();
    int chunk = (E + NB1 - 1) / NB1;
    int s = blockIdx.x * chunk, eN = min(E, s + chunk);
    for (int i = s + tid; i < eN; i += 256) atomicAdd(&h[dst[i] >> 9], 1);
    __syncthreads();
    for (int i = tid; i < NBUCK; i += 256) histG[i * NB1 + blockIdx.x] = h[i];
}

__global__ __launch_bounds__(1024) void k_scanB(int* __restrict__ histG) {
    __shared__ int ps[1024];
    int t = threadIdx.x;
    int base = t * 49;
    int vals[49];
    int sum = 0;
#pragma unroll
    for (int i = 0; i < 49; ++i) { vals[i] = histG[base + i]; sum += vals[i]; }
    ps[t] = sum;
    __syncthreads();
    for (int off = 1; off < 1024; off <<= 1) {
        int v = (t >= off) ? ps[t - off] : 0;
        __syncthreads();
        ps[t] += v;
        __syncthreads();
    }
    int run = ps[t] - sum;
#pragma unroll
    for (int i = 0; i < 49; ++i) { int v = vals[i]; histG[base + i] = run; run += v; }
}

__global__ __launch_bounds__(256) void k_place(const int* __restrict__ src,
                                               const int* __restrict__ dst,
                                               const int* __restrict__ histG,
                                               unsigned int* __restrict__ ebuf, int E) {
    __shared__ int cur[NBUCK];
    int tid = threadIdx.x;
    for (int i = tid; i < NBUCK; i += 256) cur[i] = histG[i * NB1 + blockIdx.x];
    __syncthreads();
    int chunk = (E + NB1 - 1) / NB1;
    int s = blockIdx.x * chunk, eN = min(E, s + chunk);
    for (int i = s + tid; i < eN; i += 256) {
        int d = dst[i];
        int b = d >> 9;
        int pos = atomicAdd(&cur[b], 1);
        ebuf[pos] = (unsigned int)src[i] | ((unsigned int)(d & 511) << 17);
    }
}

// one block per bucket: LDS degree count + scan, then L2-local col scatter.
// col is stored as BYTE offsets (src*256) for the bf16 row gather.
__global__ __launch_bounds__(256) void k_csr(const unsigned int* __restrict__ ebuf,
                                             const int* __restrict__ histG,
                                             int* __restrict__ rp, int* __restrict__ col,
                                             float* __restrict__ invd, int N, int E) {
    __shared__ int ldeg[512];
    __shared__ int lbase[512];
    int b = blockIdx.x, tid = threadIdx.x;
    int base = histG[b * NB1];
    int endB = (b == NBUCK - 1) ? E : histG[(b + 1) * NB1];
    int cnt = endB - base;
    int n0 = b << 9;

    ldeg[tid] = 0;
    ldeg[tid + 256] = 0;
    __syncthreads();
    for (int i = tid; i < cnt; i += 256) atomicAdd(&ldeg[ebuf[base + i] >> 17], 1);
    __syncthreads();

    int a0 = ldeg[tid], a1 = ldeg[tid + 256];
    lbase[tid] = a0;
    lbase[tid + 256] = a1;
    __syncthreads();
    for (int off = 1; off < 512; off <<= 1) {
        int v0 = (tid >= off) ? lbase[tid - off] : 0;
        int v1 = (tid + 256 >= off) ? lbase[tid + 256 - off] : 0;
        __syncthreads();
        lbase[tid] += v0;
        lbase[tid + 256] += v1;
        __syncthreads();
    }
    int e0 = lbase[tid] - a0, e1 = lbase[tid + 256] - a1;
    __syncthreads();
    lbase[tid] = e0;
    lbase[tid + 256] = e1;
    ldeg[tid] = 0;
    ldeg[tid + 256] = 0;
    __syncthreads();

    for (int i = tid; i < cnt; i += 256) {
        unsigned int p = ebuf[base + i];
        int dl = p >> 17;
        int pos = base + lbase[dl] + atomicAdd(&ldeg[dl], 1);
        col[pos] = (int)(p & 0x1FFFFu) << 8;   // byte offset into 256B bf16 rows
    }

    int g0 = n0 + tid, g1 = n0 + tid + 256;
    if (g0 < N) { rp[g0] = base + e0; invd[g0] = 1.0f / fmaxf((float)a0, 1.0f); }
    if (g1 < N) { rp[g1] = base + e1; invd[g1] = 1.0f / fmaxf((float)a1, 1.0f); }
    if (b == NBUCK - 1 && tid == 0) rp[N] = E;
    if (b == NBUCK - 1 && tid < 32) col[E + tid] = 0;   // slack for tail over-read
}

// ---------------- prep: f32 -> bf16 conversions / weight packing ----------------

__global__ void k_cvt(const float* __restrict__ x, unsigned short* __restrict__ xb, int n8) {
    int t = blockIdx.x * 256 + threadIdx.x;
    if (t >= n8) return;
    f4 a = *(const f4*)&x[(size_t)t * 8];
    f4 b = *(const f4*)&x[(size_t)t * 8 + 4];
    s16x8 p;
    p[0] = (short)f2bf(a[0]); p[1] = (short)f2bf(a[1]);
    p[2] = (short)f2bf(a[2]); p[3] = (short)f2bf(a[3]);
    p[4] = (short)f2bf(b[0]); p[5] = (short)f2bf(b[1]);
    p[6] = (short)f2bf(b[2]); p[7] = (short)f2bf(b[3]);
    *(s16x8*)&xb[(size_t)t * 8] = p;
}

// pack W^T fragments: wp[layer][ks(8)][nfg(8)][lane(64)][8]; k<128 -> ws, else wn
__global__ void k_prepw(const float* __restrict__ ws, const float* __restrict__ wn,
                        unsigned short* __restrict__ wp) {
    int t = blockIdx.x * 256 + threadIdx.x;
    if (t >= 5 * 4096) return;
    int l = t & 63, nfg = (t >> 6) & 7, ks = (t >> 9) & 7, lyr = t >> 12;
    int n = nfg * 16 + (l & 15);
    s16x8 p;
#pragma unroll
    for (int j = 0; j < 8; ++j) {
        int k = ks * 32 + (l >> 4) * 8 + j;
        float v = (k < 128) ? ws[((size_t)lyr * 128 + k) * 128 + n]
                            : wn[((size_t)lyr * 128 + (k - 128)) * 128 + n];
        p[j] = (short)f2bf(v);
    }
    *(s16x8*)&wp[(size_t)t * 8] = p;
}

// pack output-layer W^T fragments, separate self/neigh tables (K=128 each):
// wS/wN[ks(4)][nf(3)][lane(64)][8], cols >=47 zero. Also bo48 (padded bias).
__global__ void k_prepwo(const float* __restrict__ wso, const float* __restrict__ wno,
                         unsigned short* __restrict__ wS, unsigned short* __restrict__ wN,
                         const float* __restrict__ bo, float* __restrict__ bo48) {
    int t = blockIdx.x * 256 + threadIdx.x;
    if (t < 48) bo48[t] = (t < 47) ? bo[t] : 0.f;
    if (t >= 2 * 768) return;
    int tbl = t / 768, r = t % 768;
    int ks = r / 192, nf = (r / 64) % 3, l = r & 63;
    int n = nf * 16 + (l & 15);
    const float* W = tbl ? wno : wso;
    unsigned short* dstp = tbl ? wN : wS;
    s16x8 p;
#pragma unroll
    for (int j = 0; j < 8; ++j) {
        int k = ks * 32 + (l >> 4) * 8 + j;
        float v = (n < 47) ? W[(size_t)k * 47 + n] : 0.f;
        p[j] = (short)f2bf(v);
    }
    *(s16x8*)&dstp[(size_t)r * 8] = p;
}

// ---------------- mean aggregation, dwordx4 gather (4 edges per instruction) ---
// Lane i serves edge e + (i>>4), bytes (i&15)*16 of that 256B row. 16-edge
// pipelined block (4 loads in flight), then 8-edge loop, then masked tail.

__global__ __launch_bounds__(256) void k_agg(const unsigned short* __restrict__ h,
                                             const int* __restrict__ rp,
                                             const int* __restrict__ col,
                                             const float* __restrict__ invd,
                                             unsigned short* __restrict__ out, int n) {
    int gw = (blockIdx.x * 256 + threadIdx.x) >> 6;
    int lane = threadIdx.x & 63;
    if (gw >= n) return;
    const char* hb = (const char*)h;
    const int sub = lane >> 4;          // edge slot within quad
    const int lb = (lane & 15) * 16;    // byte chunk within 256B row
    int beg = rp[gw], end = rp[gw + 1];
    f2 a0 = {0.f, 0.f}, a1 = {0.f, 0.f}, a2 = {0.f, 0.f}, a3 = {0.f, 0.f};
    int e = beg;
    for (; e + 16 <= end; e += 16) {
        unsigned int c0 = (unsigned int)col[e + sub];
        unsigned int c1 = (unsigned int)col[e + 4 + sub];
        unsigned int c2 = (unsigned int)col[e + 8 + sub];
        unsigned int c3 = (unsigned int)col[e + 12 + sub];
        i4 u0, u1, u2, u3;
        __builtin_memcpy(&u0, hb + c0 + lb, 16);
        __builtin_memcpy(&u1, hb + c1 + lb, 16);
        __builtin_memcpy(&u2, hb + c2 + lb, 16);
        __builtin_memcpy(&u3, hb + c3 + lb, 16);
        acc8(a0, a1, a2, a3, u0);
        acc8(a0, a1, a2, a3, u1);
        acc8(a0, a1, a2, a3, u2);
        acc8(a0, a1, a2, a3, u3);
    }
    if (e + 8 <= end) {
        unsigned int c0 = (unsigned int)col[e + sub];
        unsigned int c1 = (unsigned int)col[e + 4 + sub];
        i4 u0, u1;
        __builtin_memcpy(&u0, hb + c0 + lb, 16);
        __builtin_memcpy(&u1, hb + c1 + lb, 16);
        acc8(a0, a1, a2, a3, u0);
        acc8(a0, a1, a2, a3, u1);
        e += 8;
    }
    if (e < end) {
        // masked tail (1..7 edges); col slack (>=32 zeros) keeps reads in-bounds
        unsigned int c0 = (unsigned int)col[e + sub];
        unsigned int c1 = (unsigned int)col[e + 4 + sub];
        i4 u0, u1;
        __builtin_memcpy(&u0, hb + c0 + lb, 16);
        __builtin_memcpy(&u1, hb + c1 + lb, 16);
        if (e + sub < end) acc8(a0, a1, a2, a3, u0);
        if (e + 4 + sub < end) acc8(a0, a1, a2, a3, u1);
    }
    // reduce the 4 edge-slots: lanes {i, i^16, i^32, i^48} hold the same chunk
#pragma unroll
    for (int off = 16; off <= 32; off <<= 1) {
        a0[0] += __shfl_xor(a0[0], off); a0[1] += __shfl_xor(a0[1], off);
        a1[0] += __shfl_xor(a1[0], off); a1[1] += __shfl_xor(a1[1], off);
        a2[0] += __shfl_xor(a2[0], off); a2[1] += __shfl_xor(a2[1], off);
        a3[0] += __shfl_xor(a3[0], off); a3[1] += __shfl_xor(a3[1], off);
    }
    if (lane < 16) {
        float iv = invd[gw];
        i4 r;
        r[0] = (int)((unsigned int)f2bf(a0[0] * iv) | ((unsigned int)f2bf(a0[1] * iv) << 16));
        r[1] = (int)((unsigned int)f2bf(a1[0] * iv) | ((unsigned int)f2bf(a1[1] * iv) << 16));
        r[2] = (int)((unsigned int)f2bf(a2[0] * iv) | ((unsigned int)f2bf(a2[1] * iv) << 16));
        r[3] = (int)((unsigned int)f2bf(a3[0] * iv) | ((unsigned int)f2bf(a3[1] * iv) << 16));
        *(i4*)((char*)out + (size_t)gw * 256 + lb) = r;
    }
}

// ---------------- fused dual MFMA GEMM (LDS-staged via global_load_lds) --------
// out = relu?(h@Ws + nb@Wn + b). 128-row tile, K=256 (h|nb), N=128. 4 waves.

__global__ __launch_bounds__(256) void gemm128(const unsigned short* __restrict__ h,
                                               const unsigned short* __restrict__ nb,
                                               const unsigned short* __restrict__ wl,
                                               const float* __restrict__ bias,
                                               unsigned short* __restrict__ out,
                                               int M, int relu) {
    __shared__ s16x8 afr[4096];  // [ks(8)][mf(8)][lane(64)] : 64 KB
    const int tid = threadIdx.x;
    const int l = tid & 63, w = tid >> 6;
    const int r0 = blockIdx.x * 128;
    const int cg = (w * 4 + (l >> 4)) * 8;

#pragma unroll
    for (int i = 0; i < 8; ++i) {
        int r = r0 + i * 16 + (l & 15);
        if (r >= M) r = M - 1;
        GLDS(h + (size_t)r * 128 + cg, &afr[(w * 8 + i) * 64]);
        GLDS(nb + (size_t)r * 128 + cg, &afr[((w + 4) * 8 + i) * 64]);
    }
    asm volatile("s_waitcnt vmcnt(0)");
    __syncthreads();

    const int mh = w >> 1, nh = w & 1;
    const s16x8* wf = (const s16x8*)wl;

    f32x4 acc[4][4];
#pragma unroll
    for (int i = 0; i < 4; ++i)
#pragma unroll
        for (int j = 0; j < 4; ++j) acc[i][j] = (f32x4)0.f;

#pragma unroll
    for (int ks = 0; ks < 8; ++ks) {
        s16x8 bw[4], ha[4];
#pragma unroll
        for (int nf = 0; nf < 4; ++nf) bw[nf] = wf[(ks * 8 + nh * 4 + nf) * 64 + l];
#pragma unroll
        for (int mf = 0; mf < 4; ++mf) ha[mf] = afr[(ks * 8 + mh * 4 + mf) * 64 + l];
#pragma unroll
        for (int mf = 0; mf < 4; ++mf)
#pragma unroll
            for (int nf = 0; nf < 4; ++nf)
                acc[mf][nf] = __builtin_amdgcn_mfma_f32_16x16x32_bf16(bw[nf], ha[mf],
                                                                      acc[mf][nf], 0, 0, 0);
    }

    f4 bv[4];
#pragma unroll
    for (int nf = 0; nf < 4; ++nf)
        bv[nf] = *(const f4*)&bias[nh * 64 + nf * 16 + ((l >> 4) << 2)];

#pragma unroll
    for (int mf = 0; mf < 4; ++mf) {
        int row = r0 + mh * 64 + mf * 16 + (l & 15);
        if (row >= M) continue;
#pragma unroll
        for (int nf = 0; nf < 4; ++nf) {
            int ncol = nh * 64 + nf * 16 + ((l >> 4) << 2);
            f32x4 a = acc[mf][nf];
            float v0 = a[0] + bv[nf][0], v1 = a[1] + bv[nf][1];
            float v2 = a[2] + bv[nf][2], v3 = a[3] + bv[nf][3];
            if (relu) {
                v0 = fmaxf(v0, 0.f); v1 = fmaxf(v1, 0.f);
                v2 = fmaxf(v2, 0.f); v3 = fmaxf(v3, 0.f);
            }
            uint2 p;
            p.x = (unsigned int)f2bf(v0) | ((unsigned int)f2bf(v1) << 16);
            p.y = (unsigned int)f2bf(v2) | ((unsigned int)f2bf(v3) << 16);
            *(uint2*)(out + (size_t)row * 128 + ncol) = p;
        }
    }
}

// ---------------- final layer, dense part: tmpn = h@wno (bf16), selfo = h@wso+bo
// Block = 64 rows, 4 waves (2 row-halves x {self, neigh}).

__global__ __launch_bounds__(256) void gemm_fin(const unsigned short* __restrict__ h,
                                                const unsigned short* __restrict__ wS,
                                                const unsigned short* __restrict__ wN,
                                                const float* __restrict__ bo48,
                                                unsigned short* __restrict__ tmpn,
                                                float* __restrict__ selfo, int M) {
    const int tid = threadIdx.x;
    const int l = tid & 63, wv = tid >> 6;
    const int mh = wv >> 1, sel = wv & 1;   // sel: 0 = self (f32+bias), 1 = neigh (bf16)
    const int r0 = blockIdx.x * 64;
    const s16x8* wf = (const s16x8*)(sel ? wN : wS);
    const int cgb = (l >> 4) << 3;

    int R[2];
#pragma unroll
    for (int mf = 0; mf < 2; ++mf) {
        int r = r0 + mh * 32 + mf * 16 + (l & 15);
        R[mf] = (r > M - 1) ? (M - 1) : r;
    }

    f32x4 acc[2][3];
#pragma unroll
    for (int i = 0; i < 2; ++i)
#pragma unroll
        for (int j = 0; j < 3; ++j) acc[i][j] = (f32x4)0.f;

#pragma unroll
    for (int ks = 0; ks < 4; ++ks) {
        s16x8 ha[2];
#pragma unroll
        for (int mf = 0; mf < 2; ++mf)
            ha[mf] = *(const s16x8*)(h + (size_t)R[mf] * 128 + ks * 32 + cgb);
#pragma unroll
        for (int nf = 0; nf < 3; ++nf) {
            s16x8 bw = wf[(ks * 3 + nf) * 64 + l];
            acc[0][nf] = __builtin_amdgcn_mfma_f32_16x16x32_bf16(bw, ha[0], acc[0][nf], 0, 0, 0);
            acc[1][nf] = __builtin_amdgcn_mfma_f32_16x16x32_bf16(bw, ha[1], acc[1][nf], 0, 0, 0);
        }
    }

#pragma unroll
    for (int mf = 0; mf < 2; ++mf) {
        int row = r0 + mh * 32 + mf * 16 + (l & 15);
        if (row >= M) continue;
#pragma unroll
        for (int nf = 0; nf < 3; ++nf) {
            int ncol = nf * 16 + ((l >> 4) << 2);
            f32x4 a = acc[mf][nf];
            if (sel == 0) {
                f4 bv = *(const f4*)&bo48[ncol];
                f4 o;
                o[0] = a[0] + bv[0]; o[1] = a[1] + bv[1];
                o[2] = a[2] + bv[2]; o[3] = a[3] + bv[3];
                *(f4*)&selfo[(size_t)row * 48 + ncol] = o;
            } else {
                uint2 p;
                p.x = (unsigned int)f2bf(a[0]) | ((unsigned int)f2bf(a[1]) << 16);
                p.y = (unsigned int)f2bf(a[2]) | ((unsigned int)f2bf(a[3]) << 16);
                *(uint2*)(tmpn + (size_t)row * 64 + ncol) = p;
            }
        }
    }
}

// ---------------- final aggregation over 128B rows (R9-proven form) ------------
// One wave per node; 32 lanes per edge -> 2 rows per gather instruction,
// 4 loads in flight per 8-edge iteration.

__global__ __launch_bounds__(256) void k_agg_fin(const unsigned short* __restrict__ z,
                                                 const float* __restrict__ selfo,
                                                 const int* __restrict__ rp,
                                                 const int* __restrict__ col,
                                                 const float* __restrict__ invd,
                                                 float* __restrict__ out, int n) {
    int gw = (blockIdx.x * 256 + threadIdx.x) >> 6;
    int lane = threadIdx.x & 63;
    if (gw >= n) return;
    const char* zb = (const char*)z;
    const int hhalf = lane >> 5;        // 0: even edges, 1: odd edges
    const int lb = (lane & 31) * 4;     // byte within 128B row
    int beg = rp[gw], end = rp[gw + 1];
    f2 acc = {0.f, 0.f};
    int e = beg;
    for (; e + 8 <= end; e += 8) {
        unsigned int u[4];
#pragma unroll
        for (int j = 0; j < 4; ++j) {
            unsigned int c = (unsigned int)col[e + 2 * j + hhalf];  // src*256
            u[j] = *(const unsigned int*)(zb + (c >> 1) + lb);
        }
#pragma unroll
        for (int j = 0; j < 4; ++j) { f2 v = {bflo(u[j]), bfhi(u[j])}; acc += v; }
    }
    if (e < end) {
        int rem = end - e;  // 1..7; col slack (>=32 zeros) makes reads safe
        unsigned int u[4];
#pragma unroll
        for (int j = 0; j < 4; ++j) {
            unsigned int c = (unsigned int)col[e + 2 * j + hhalf];
            u[j] = *(const unsigned int*)(zb + (c >> 1) + lb);
        }
#pragma unroll
        for (int j = 0; j < 4; ++j) {
            if (2 * j + hhalf < rem) { f2 v = {bflo(u[j]), bfhi(u[j])}; acc += v; }
        }
    }
    // combine the two half-wave partial sums (lane l <-> l+32 hold same cols)
    f2 tot;
    tot[0] = acc[0] + __shfl_xor(acc[0], 32);
    tot[1] = acc[1] + __shfl_xor(acc[1], 32);
    float iv = invd[gw];
    if (lane < 24) {
        int c0 = lane * 2;   // cols c0, c0+1 (real cols are 0..46)
        f2 s = *(const f2*)&selfo[(size_t)gw * 48 + c0];
        out[(size_t)gw * 47 + c0] = s[0] + tot[0] * iv;
        if (c0 + 1 < 47) out[(size_t)gw * 47 + c0 + 1] = s[1] + tot[1] * iv;
    }
}

// ---------------- launch ----------------

static inline char* alignp(char* p) {
    return (char*)(((size_t)p + 255) & ~(size_t)255);
}

extern "C" void kernel_launch(void* const* d_in, const int* in_sizes, int n_in,
                              void* d_out, int out_size, void* d_ws, size_t ws_size,
                              hipStream_t stream) {
    const float* x = (const float*)d_in[0];
    const int* src = (const int*)d_in[1];
    const int* dst = (const int*)d_in[2];
    const float* w_self = (const float*)d_in[3];
    const float* w_neigh = (const float*)d_in[4];
    const float* b = (const float*)d_in[5];
    const float* wso = (const float*)d_in[6];
    const float* wno = (const float*)d_in[7];
    const float* bo = (const float*)d_in[8];
    float* out = (float*)d_out;

    const int N = N_NODES;
    const int E = in_sizes[1];

    char* w = (char*)d_ws;
    unsigned short* xb = (unsigned short*)w;   w = alignp(w + (size_t)N * 128 * 2);
    unsigned short* hA = (unsigned short*)w;   w = alignp(w + (size_t)N * 128 * 2);
    unsigned short* hB = (unsigned short*)w;   w = alignp(w + (size_t)N * 128 * 2);
    unsigned short* nbuf = (unsigned short*)w; w = alignp(w + (size_t)N * 128 * 2);
    unsigned short* wp = (unsigned short*)w;   w = alignp(w + (size_t)5 * 32768 * 2);
    unsigned short* wS = (unsigned short*)w;   w = alignp(w + (size_t)768 * 8 * 2);
    unsigned short* wN = (unsigned short*)w;   w = alignp(w + (size_t)768 * 8 * 2);
    float* bo48 = (float*)w; w = alignp(w + 48 * 4);
    int* rp = (int*)w;       w = alignp(w + (size_t)(N + 4) * 4);
    int* col = (int*)w;      w = alignp(w + (size_t)(E + 32) * 4);
    int* histG = (int*)w;    w = alignp(w + (size_t)NBUCK * NB1 * 4);
    float* invd = (float*)w; w = alignp(w + (size_t)N * 4);

    // Aliases (lifetimes disjoint):
    // ebuf (packed edges) lives in hB: hB first written at layer-1 GEMM output.
    unsigned int* ebuf = (unsigned int*)hB;
    // final layer: tmpn (100K x 64 bf16) in nbuf; selfo (100K x 48 f32) in hB.
    unsigned short* tmpn = nbuf;

    // CSR build (bucketed, L2-local scatters)
    k_hist<<<NB1, 256, 0, stream>>>(dst, histG, E);
    k_scanB<<<1, 1024, 0, stream>>>(histG);
    k_place<<<NB1, 256, 0, stream>>>(src, dst, histG, ebuf, E);
    k_csr<<<NBUCK, 256, 0, stream>>>(ebuf, histG, rp, col, invd, N, E);

    // dtype prep
    k_cvt<<<(N * 128 / 8 + 255) / 256, 256, 0, stream>>>(x, xb, N * 128 / 8);
    k_prepw<<<(5 * 4096 + 255) / 256, 256, 0, stream>>>(w_self, w_neigh, wp);
    k_prepwo<<<6, 256, 0, stream>>>(wso, wno, wS, wN, bo, bo48);

    const int aggBlocks = (N * 64 + 255) / 256;   // 25000
    const int gemmBlocks = (N + 127) / 128;       // 782
    const int finBlocks = (N + 63) / 64;          // 1563

    // layer 0 (no relu): agg(xb)->nbuf, gemm -> hA
    k_agg<<<aggBlocks, 256, 0, stream>>>(xb, rp, col, invd, nbuf, N);
    gemm128<<<gemmBlocks, 256, 0, stream>>>(xb, nbuf, wp, b, hA, N, 0);

    unsigned short* cur = hA;
    unsigned short* oth = hB;
    for (int lyr = 1; lyr < 5; ++lyr) {
        k_agg<<<aggBlocks, 256, 0, stream>>>(cur, rp, col, invd, nbuf, N);
        gemm128<<<gemmBlocks, 256, 0, stream>>>(cur, nbuf, wp + (size_t)lyr * 32768,
                                                b + (size_t)lyr * 128, oth, N, 1);
        unsigned short* t = cur; cur = oth; oth = t;
    }
    // after L0..L4: cur == hA, oth == hB

    // final layer: dense transforms first, then 128B-row aggregation
    float* selfo = (float*)hB;
    gemm_fin<<<finBlocks, 256, 0, stream>>>(cur, wS, wN, bo48, tmpn, selfo, N);
    k_agg_fin<<<aggBlocks, 256, 0, stream>>>(tmpn, selfo, rp, col, invd, out, N);
}

// Round 12
// 550.842 us; speedup vs baseline: 1.0740x; 1.0192x over previous
//
#include <hip/hip_runtime.h>

typedef float f4 __attribute__((ext_vector_type(4)));
typedef float f32x4 __attribute__((ext_vector_type(4)));
typedef float f2 __attribute__((ext_vector_type(2)));
typedef short s16x8 __attribute__((ext_vector_type(8)));
typedef int i4 __attribute__((ext_vector_type(4)));

#define N_NODES 100000
#define NBUCK 196   // ceil(100000/512)
#define NB1 256     // blocks in hist/place passes

__device__ inline unsigned short f2bf(float f) {
    unsigned int u = __builtin_bit_cast(unsigned int, f);
    u += 0x7FFFu + ((u >> 16) & 1u);
    return (unsigned short)(u >> 16);
}
__device__ inline float bflo(unsigned int v) { return __builtin_bit_cast(float, v << 16); }
__device__ inline float bfhi(unsigned int v) { return __builtin_bit_cast(float, v & 0xFFFF0000u); }

// async global->LDS, 16B per lane; LDS dest is wave-uniform base + lane*16
#define GLDS(gp, lp)                                                            \
    __builtin_amdgcn_global_load_lds(                                           \
        (const __attribute__((address_space(1))) void*)(gp),                    \
        (__attribute__((address_space(3))) void*)(lp), 16, 0, 0)

// accumulate 4 dwords (8 bf16) into 4 f2 accumulators
__device__ inline void acc8(f2& a0, f2& a1, f2& a2, f2& a3, i4 u) {
    f2 t0 = {bflo((unsigned int)u[0]), bfhi((unsigned int)u[0])};
    f2 t1 = {bflo((unsigned int)u[1]), bfhi((unsigned int)u[1])};
    f2 t2 = {bflo((unsigned int)u[2]), bfhi((unsigned int)u[2])};
    f2 t3 = {bflo((unsigned int)u[3]), bfhi((unsigned int)u[3])};
    a0 += t0; a1 += t1; a2 += t2; a3 += t3;
}

// ---------------- bucketed CSR build ----------------
// bucket = dst >> 9 (512 nodes per bucket); edge packed as src | (dst&511)<<17

__global__ __launch_bounds__(256) void k_hist(const int* __restrict__ dst,
                                              int* __restrict__ histG, int E) {
    __shared__ int h[NBUCK];
    int tid = threadIdx.x;
    for (int i = tid; i < NBUCK; i += 256) h[i] = 0;
    __syncthreads();
    int chunk = (E + NB1 - 1) / NB1;
    int s = blockIdx.x * chunk, eN = min(E, s + chunk);
    for (int i = s + tid; i < eN; i += 256) atomicAdd(&h[dst[i] >> 9], 1);
    __syncthreads();
    for (int i = tid; i < NBUCK; i += 256) histG[i * NB1 + blockIdx.x] = h[i];
}

__global__ __launch_bounds__(1024) void k_scanB(int* __restrict__ histG) {
    __shared__ int ps[1024];
    int t = threadIdx.x;
    int base = t * 49;
    int vals[49];
    int sum = 0;
#pragma unroll
    for (int i = 0; i < 49; ++i) { vals[i] = histG[base + i]; sum += vals[i]; }
    ps[t] = sum;
    __syncthreads();
    for (int off = 1; off < 1024; off <<= 1) {
        int v = (t >= off) ? ps[t - off] : 0;
        __syncthreads();
        ps[t] += v;
        __syncthreads();
    }
    int run = ps[t] - sum;
#pragma unroll
    for (int i = 0; i < 49; ++i) { int v = vals[i]; histG[base + i] = run; run += v; }
}

__global__ __launch_bounds__(256) void k_place(const int* __restrict__ src,
                                               const int* __restrict__ dst,
                                               const int* __restrict__ histG,
                                               unsigned int* __restrict__ ebuf, int E) {
    __shared__ int cur[NBUCK];
    int tid = threadIdx.x;
    for (int i = tid; i < NBUCK; i += 256) cur[i] = histG[i * NB1 + blockIdx.x];
    __syncthreads();
    int chunk = (E + NB1 - 1) / NB1;
    int s = blockIdx.x * chunk, eN = min(E, s + chunk);
    for (int i = s + tid; i < eN; i += 256) {
        int d = dst[i];
        int b = d >> 9;
        int pos = atomicAdd(&cur[b], 1);
        ebuf[pos] = (unsigned int)src[i] | ((unsigned int)(d & 511) << 17);
    }
}

// one block per bucket: LDS degree count + scan, then L2-local col scatter.
// col is stored as BYTE offsets (src*256) for the bf16 row gather.
__global__ __launch_bounds__(256) void k_csr(const unsigned int* __restrict__ ebuf,
                                             const int* __restrict__ histG,
                                             int* __restrict__ rp, int* __restrict__ col,
                                             float* __restrict__ invd, int N, int E) {
    __shared__ int ldeg[512];
    __shared__ int lbase[512];
    int b = blockIdx.x, tid = threadIdx.x;
    int base = histG[b * NB1];
    int endB = (b == NBUCK - 1) ? E : histG[(b + 1) * NB1];
    int cnt = endB - base;
    int n0 = b << 9;

    ldeg[tid] = 0;
    ldeg[tid + 256] = 0;
    __syncthreads();
    for (int i = tid; i < cnt; i += 256) atomicAdd(&ldeg[ebuf[base + i] >> 17], 1);
    __syncthreads();

    int a0 = ldeg[tid], a1 = ldeg[tid + 256];
    lbase[tid] = a0;
    lbase[tid + 256] = a1;
    __syncthreads();
    for (int off = 1; off < 512; off <<= 1) {
        int v0 = (tid >= off) ? lbase[tid - off] : 0;
        int v1 = (tid + 256 >= off) ? lbase[tid + 256 - off] : 0;
        __syncthreads();
        lbase[tid] += v0;
        lbase[tid + 256] += v1;
        __syncthreads();
    }
    int e0 = lbase[tid] - a0, e1 = lbase[tid + 256] - a1;
    __syncthreads();
    lbase[tid] = e0;
    lbase[tid + 256] = e1;
    ldeg[tid] = 0;
    ldeg[tid + 256] = 0;
    __syncthreads();

    for (int i = tid; i < cnt; i += 256) {
        unsigned int p = ebuf[base + i];
        int dl = p >> 17;
        int pos = base + lbase[dl] + atomicAdd(&ldeg[dl], 1);
        col[pos] = (int)(p & 0x1FFFFu) << 8;   // byte offset into 256B bf16 rows
    }

    int g0 = n0 + tid, g1 = n0 + tid + 256;
    if (g0 < N) { rp[g0] = base + e0; invd[g0] = 1.0f / fmaxf((float)a0, 1.0f); }
    if (g1 < N) { rp[g1] = base + e1; invd[g1] = 1.0f / fmaxf((float)a1, 1.0f); }
    if (b == NBUCK - 1 && tid == 0) rp[N] = E;
    if (b == NBUCK - 1 && tid < 32) col[E + tid] = 0;   // slack for tail over-read
}

// ---------------- prep: f32 -> bf16 conversions / weight packing ----------------

__global__ void k_cvt(const float* __restrict__ x, unsigned short* __restrict__ xb, int n8) {
    int t = blockIdx.x * 256 + threadIdx.x;
    if (t >= n8) return;
    f4 a = *(const f4*)&x[(size_t)t * 8];
    f4 b = *(const f4*)&x[(size_t)t * 8 + 4];
    s16x8 p;
    p[0] = (short)f2bf(a[0]); p[1] = (short)f2bf(a[1]);
    p[2] = (short)f2bf(a[2]); p[3] = (short)f2bf(a[3]);
    p[4] = (short)f2bf(b[0]); p[5] = (short)f2bf(b[1]);
    p[6] = (short)f2bf(b[2]); p[7] = (short)f2bf(b[3]);
    *(s16x8*)&xb[(size_t)t * 8] = p;
}

// pack W^T fragments: wp[layer][ks(8)][nfg(8)][lane(64)][8]; k<128 -> ws, else wn
__global__ void k_prepw(const float* __restrict__ ws, const float* __restrict__ wn,
                        unsigned short* __restrict__ wp) {
    int t = blockIdx.x * 256 + threadIdx.x;
    if (t >= 5 * 4096) return;
    int l = t & 63, nfg = (t >> 6) & 7, ks = (t >> 9) & 7, lyr = t >> 12;
    int n = nfg * 16 + (l & 15);
    s16x8 p;
#pragma unroll
    for (int j = 0; j < 8; ++j) {
        int k = ks * 32 + (l >> 4) * 8 + j;
        float v = (k < 128) ? ws[((size_t)lyr * 128 + k) * 128 + n]
                            : wn[((size_t)lyr * 128 + (k - 128)) * 128 + n];
        p[j] = (short)f2bf(v);
    }
    *(s16x8*)&wp[(size_t)t * 8] = p;
}

// pack output-layer W^T fragments, separate self/neigh tables (K=128 each):
// wS/wN[ks(4)][nf(3)][lane(64)][8], cols >=47 zero. Also bo48 (padded bias).
__global__ void k_prepwo(const float* __restrict__ wso, const float* __restrict__ wno,
                         unsigned short* __restrict__ wS, unsigned short* __restrict__ wN,
                         const float* __restrict__ bo, float* __restrict__ bo48) {
    int t = blockIdx.x * 256 + threadIdx.x;
    if (t < 48) bo48[t] = (t < 47) ? bo[t] : 0.f;
    if (t >= 2 * 768) return;
    int tbl = t / 768, r = t % 768;
    int ks = r / 192, nf = (r / 64) % 3, l = r & 63;
    int n = nf * 16 + (l & 15);
    const float* W = tbl ? wno : wso;
    unsigned short* dstp = tbl ? wN : wS;
    s16x8 p;
#pragma unroll
    for (int j = 0; j < 8; ++j) {
        int k = ks * 32 + (l >> 4) * 8 + j;
        float v = (n < 47) ? W[(size_t)k * 47 + n] : 0.f;
        p[j] = (short)f2bf(v);
    }
    *(s16x8*)&dstp[(size_t)r * 8] = p;
}

// ---------------- mean aggregation, dwordx4 gather (R10-proven form) -----------
// Lane i serves edge e + (i>>4), bytes (i&15)*16 of that 256B row.

__global__ __launch_bounds__(256) void k_agg(const unsigned short* __restrict__ h,
                                             const int* __restrict__ rp,
                                             const int* __restrict__ col,
                                             const float* __restrict__ invd,
                                             unsigned short* __restrict__ out, int n) {
    int gw = (blockIdx.x * 256 + threadIdx.x) >> 6;
    int lane = threadIdx.x & 63;
    if (gw >= n) return;
    const char* hb = (const char*)h;
    const int sub = lane >> 4;          // edge slot within quad
    const int lb = (lane & 15) * 16;    // byte chunk within 256B row
    int beg = rp[gw], end = rp[gw + 1];
    f2 a0 = {0.f, 0.f}, a1 = {0.f, 0.f}, a2 = {0.f, 0.f}, a3 = {0.f, 0.f};
    int e = beg;
    for (; e + 8 <= end; e += 8) {
        unsigned int c0 = (unsigned int)col[e + sub];
        unsigned int c1 = (unsigned int)col[e + 4 + sub];
        i4 u, v;
        __builtin_memcpy(&u, hb + c0 + lb, 16);
        __builtin_memcpy(&v, hb + c1 + lb, 16);
        acc8(a0, a1, a2, a3, u);
        acc8(a0, a1, a2, a3, v);
    }
    if (e < end) {
        // masked tail (1..7 edges); col slack (>=32 zeros) keeps reads in-bounds
        unsigned int c0 = (unsigned int)col[e + sub];
        unsigned int c1 = (unsigned int)col[e + 4 + sub];
        i4 u, v;
        __builtin_memcpy(&u, hb + c0 + lb, 16);
        __builtin_memcpy(&v, hb + c1 + lb, 16);
        if (e + sub < end) acc8(a0, a1, a2, a3, u);
        if (e + 4 + sub < end) acc8(a0, a1, a2, a3, v);
    }
    // reduce the 4 edge-slots: lanes {i, i^16, i^32, i^48} hold the same chunk
#pragma unroll
    for (int off = 16; off <= 32; off <<= 1) {
        a0[0] += __shfl_xor(a0[0], off); a0[1] += __shfl_xor(a0[1], off);
        a1[0] += __shfl_xor(a1[0], off); a1[1] += __shfl_xor(a1[1], off);
        a2[0] += __shfl_xor(a2[0], off); a2[1] += __shfl_xor(a2[1], off);
        a3[0] += __shfl_xor(a3[0], off); a3[1] += __shfl_xor(a3[1], off);
    }
    if (lane < 16) {
        float iv = invd[gw];
        i4 r;
        r[0] = (int)((unsigned int)f2bf(a0[0] * iv) | ((unsigned int)f2bf(a0[1] * iv) << 16));
        r[1] = (int)((unsigned int)f2bf(a1[0] * iv) | ((unsigned int)f2bf(a1[1] * iv) << 16));
        r[2] = (int)((unsigned int)f2bf(a2[0] * iv) | ((unsigned int)f2bf(a2[1] * iv) << 16));
        r[3] = (int)((unsigned int)f2bf(a3[0] * iv) | ((unsigned int)f2bf(a3[1] * iv) << 16));
        *(i4*)((char*)out + (size_t)gw * 256 + lb) = r;
    }
}

// ---------------- fused dual MFMA GEMM, 64-row tile, 32 KB LDS -----------------
// out = relu?(h@Ws + nb@Wn + b). 4 waves; wave w owns all 64 rows x cols w*32..+31.
// LDS slots: h -> w*4+i, nb -> 16+w*4+i (wave w stages k-quadrant w).

__global__ __launch_bounds__(256, 4) void gemm128(const unsigned short* __restrict__ h,
                                                  const unsigned short* __restrict__ nb,
                                                  const unsigned short* __restrict__ wl,
                                                  const float* __restrict__ bias,
                                                  unsigned short* __restrict__ out,
                                                  int M, int relu) {
    __shared__ s16x8 afr[2048];  // 32 slots x 64 lanes : 32 KB
    const int tid = threadIdx.x;
    const int l = tid & 63, w = tid >> 6;
    const int r0 = blockIdx.x * 64;
    const int cg = (w * 4 + (l >> 4)) * 8;

#pragma unroll
    for (int i = 0; i < 4; ++i) {
        int r = r0 + i * 16 + (l & 15);
        if (r >= M) r = M - 1;
        GLDS(h + (size_t)r * 128 + cg, &afr[(w * 4 + i) * 64]);
        GLDS(nb + (size_t)r * 128 + cg, &afr[(16 + w * 4 + i) * 64]);
    }
    asm volatile("s_waitcnt vmcnt(0)");
    __syncthreads();

    const s16x8* wf = (const s16x8*)wl;

    f32x4 acc[4][2];
#pragma unroll
    for (int i = 0; i < 4; ++i)
#pragma unroll
        for (int j = 0; j < 2; ++j) acc[i][j] = (f32x4)0.f;

#pragma unroll
    for (int ks = 0; ks < 8; ++ks) {
        const int base = (ks < 4) ? (ks * 4) : (16 + (ks - 4) * 4);
        s16x8 ha[4], bw[2];
#pragma unroll
        for (int mf = 0; mf < 4; ++mf) ha[mf] = afr[(base + mf) * 64 + l];
#pragma unroll
        for (int nf = 0; nf < 2; ++nf) bw[nf] = wf[(ks * 8 + w * 2 + nf) * 64 + l];
#pragma unroll
        for (int mf = 0; mf < 4; ++mf)
#pragma unroll
            for (int nf = 0; nf < 2; ++nf)
                acc[mf][nf] = __builtin_amdgcn_mfma_f32_16x16x32_bf16(bw[nf], ha[mf],
                                                                      acc[mf][nf], 0, 0, 0);
    }

    f4 bv[2];
#pragma unroll
    for (int nf = 0; nf < 2; ++nf)
        bv[nf] = *(const f4*)&bias[w * 32 + nf * 16 + ((l >> 4) << 2)];

#pragma unroll
    for (int mf = 0; mf < 4; ++mf) {
        int row = r0 + mf * 16 + (l & 15);
        if (row >= M) continue;
#pragma unroll
        for (int nf = 0; nf < 2; ++nf) {
            int ncol = w * 32 + nf * 16 + ((l >> 4) << 2);
            f32x4 a = acc[mf][nf];
            float v0 = a[0] + bv[nf][0], v1 = a[1] + bv[nf][1];
            float v2 = a[2] + bv[nf][2], v3 = a[3] + bv[nf][3];
            if (relu) {
                v0 = fmaxf(v0, 0.f); v1 = fmaxf(v1, 0.f);
                v2 = fmaxf(v2, 0.f); v3 = fmaxf(v3, 0.f);
            }
            uint2 p;
            p.x = (unsigned int)f2bf(v0) | ((unsigned int)f2bf(v1) << 16);
            p.y = (unsigned int)f2bf(v2) | ((unsigned int)f2bf(v3) << 16);
            *(uint2*)(out + (size_t)row * 128 + ncol) = p;
        }
    }
}

// ---------------- final layer, dense part (LDS-staged h) -----------------------
// tmpn = h@wno (bf16), selfo = h@wso + bo (f32). 64-row tile, 16 KB LDS.
// Waves: mh = wv>>1 (row half), sel = wv&1 (0 = self, 1 = neigh).

__global__ __launch_bounds__(256, 4) void gemm_fin(const unsigned short* __restrict__ h,
                                                   const unsigned short* __restrict__ wS,
                                                   const unsigned short* __restrict__ wN,
                                                   const float* __restrict__ bo48,
                                                   unsigned short* __restrict__ tmpn,
                                                   float* __restrict__ selfo, int M) {
    __shared__ s16x8 afr[1024];  // 16 slots x 64 lanes : 16 KB
    const int tid = threadIdx.x;
    const int l = tid & 63, wv = tid >> 6;
    const int r0 = blockIdx.x * 64;
    const int cg = (wv * 4 + (l >> 4)) * 8;

#pragma unroll
    for (int i = 0; i < 4; ++i) {
        int r = r0 + i * 16 + (l & 15);
        if (r >= M) r = M - 1;
        GLDS(h + (size_t)r * 128 + cg, &afr[(wv * 4 + i) * 64]);
    }
    asm volatile("s_waitcnt vmcnt(0)");
    __syncthreads();

    const int mh = wv >> 1, sel = wv & 1;
    const s16x8* wf = (const s16x8*)(sel ? wN : wS);

    f32x4 acc[2][3];
#pragma unroll
    for (int i = 0; i < 2; ++i)
#pragma unroll
        for (int j = 0; j < 3; ++j) acc[i][j] = (f32x4)0.f;

#pragma unroll
    for (int ks = 0; ks < 4; ++ks) {
        s16x8 ha[2], bw[3];
#pragma unroll
        for (int mf = 0; mf < 2; ++mf) ha[mf] = afr[(ks * 4 + mh * 2 + mf) * 64 + l];
#pragma unroll
        for (int nf = 0; nf < 3; ++nf) bw[nf] = wf[(ks * 3 + nf) * 64 + l];
#pragma unroll
        for (int mf = 0; mf < 2; ++mf)
#pragma unroll
            for (int nf = 0; nf < 3; ++nf)
                acc[mf][nf] = __builtin_amdgcn_mfma_f32_16x16x32_bf16(bw[nf], ha[mf],
                                                                      acc[mf][nf], 0, 0, 0);
    }

#pragma unroll
    for (int mf = 0; mf < 2; ++mf) {
        int row = r0 + mh * 32 + mf * 16 + (l & 15);
        if (row >= M) continue;
#pragma unroll
        for (int nf = 0; nf < 3; ++nf) {
            int ncol = nf * 16 + ((l >> 4) << 2);
            f32x4 a = acc[mf][nf];
            if (sel == 0) {
                f4 bv = *(const f4*)&bo48[ncol];
                f4 o;
                o[0] = a[0] + bv[0]; o[1] = a[1] + bv[1];
                o[2] = a[2] + bv[2]; o[3] = a[3] + bv[3];
                *(f4*)&selfo[(size_t)row * 48 + ncol] = o;
            } else {
                uint2 p;
                p.x = (unsigned int)f2bf(a[0]) | ((unsigned int)f2bf(a[1]) << 16);
                p.y = (unsigned int)f2bf(a[2]) | ((unsigned int)f2bf(a[3]) << 16);
                *(uint2*)(tmpn + (size_t)row * 64 + ncol) = p;
            }
        }
    }
}

// ---------------- final aggregation over 128B rows (R9-proven form) ------------
// One wave per node; 32 lanes per edge -> 2 rows per gather instruction.

__global__ __launch_bounds__(256) void k_agg_fin(const unsigned short* __restrict__ z,
                                                 const float* __restrict__ selfo,
                                                 const int* __restrict__ rp,
                                                 const int* __restrict__ col,
                                                 const float* __restrict__ invd,
                                                 float* __restrict__ out, int n) {
    int gw = (blockIdx.x * 256 + threadIdx.x) >> 6;
    int lane = threadIdx.x & 63;
    if (gw >= n) return;
    const char* zb = (const char*)z;
    const int hhalf = lane >> 5;        // 0: even edges, 1: odd edges
    const int lb = (lane & 31) * 4;     // byte within 128B row
    int beg = rp[gw], end = rp[gw + 1];
    f2 acc = {0.f, 0.f};
    int e = beg;
    for (; e + 8 <= end; e += 8) {
        unsigned int u[4];
#pragma unroll
        for (int j = 0; j < 4; ++j) {
            unsigned int c = (unsigned int)col[e + 2 * j + hhalf];  // src*256
            u[j] = *(const unsigned int*)(zb + (c >> 1) + lb);
        }
#pragma unroll
        for (int j = 0; j < 4; ++j) { f2 v = {bflo(u[j]), bfhi(u[j])}; acc += v; }
    }
    if (e < end) {
        int rem = end - e;  // 1..7; col slack (>=32 zeros) makes reads safe
        unsigned int u[4];
#pragma unroll
        for (int j = 0; j < 4; ++j) {
            unsigned int c = (unsigned int)col[e + 2 * j + hhalf];
            u[j] = *(const unsigned int*)(zb + (c >> 1) + lb);
        }
#pragma unroll
        for (int j = 0; j < 4; ++j) {
            if (2 * j + hhalf < rem) { f2 v = {bflo(u[j]), bfhi(u[j])}; acc += v; }
        }
    }
    // combine the two half-wave partial sums (lane l <-> l+32 hold same cols)
    f2 tot;
    tot[0] = acc[0] + __shfl_xor(acc[0], 32);
    tot[1] = acc[1] + __shfl_xor(acc[1], 32);
    float iv = invd[gw];
    if (lane < 24) {
        int c0 = lane * 2;   // cols c0, c0+1 (real cols are 0..46)
        f2 s = *(const f2*)&selfo[(size_t)gw * 48 + c0];
        out[(size_t)gw * 47 + c0] = s[0] + tot[0] * iv;
        if (c0 + 1 < 47) out[(size_t)gw * 47 + c0 + 1] = s[1] + tot[1] * iv;
    }
}

// ---------------- launch ----------------

static inline char* alignp(char* p) {
    return (char*)(((size_t)p + 255) & ~(size_t)255);
}

extern "C" void kernel_launch(void* const* d_in, const int* in_sizes, int n_in,
                              void* d_out, int out_size, void* d_ws, size_t ws_size,
                              hipStream_t stream) {
    const float* x = (const float*)d_in[0];
    const int* src = (const int*)d_in[1];
    const int* dst = (const int*)d_in[2];
    const float* w_self = (const float*)d_in[3];
    const float* w_neigh = (const float*)d_in[4];
    const float* b = (const float*)d_in[5];
    const float* wso = (const float*)d_in[6];
    const float* wno = (const float*)d_in[7];
    const float* bo = (const float*)d_in[8];
    float* out = (float*)d_out;

    const int N = N_NODES;
    const int E = in_sizes[1];

    char* w = (char*)d_ws;
    unsigned short* xb = (unsigned short*)w;   w = alignp(w + (size_t)N * 128 * 2);
    unsigned short* hA = (unsigned short*)w;   w = alignp(w + (size_t)N * 128 * 2);
    unsigned short* hB = (unsigned short*)w;   w = alignp(w + (size_t)N * 128 * 2);
    unsigned short* nbuf = (unsigned short*)w; w = alignp(w + (size_t)N * 128 * 2);
    unsigned short* wp = (unsigned short*)w;   w = alignp(w + (size_t)5 * 32768 * 2);
    unsigned short* wS = (unsigned short*)w;   w = alignp(w + (size_t)768 * 8 * 2);
    unsigned short* wN = (unsigned short*)w;   w = alignp(w + (size_t)768 * 8 * 2);
    float* bo48 = (float*)w; w = alignp(w + 48 * 4);
    int* rp = (int*)w;       w = alignp(w + (size_t)(N + 4) * 4);
    int* col = (int*)w;      w = alignp(w + (size_t)(E + 32) * 4);
    int* histG = (int*)w;    w = alignp(w + (size_t)NBUCK * NB1 * 4);
    float* invd = (float*)w; w = alignp(w + (size_t)N * 4);

    // Aliases (lifetimes disjoint):
    // ebuf (packed edges) lives in hB: hB first written at layer-1 GEMM output.
    unsigned int* ebuf = (unsigned int*)hB;
    // final layer: tmpn (100K x 64 bf16) in nbuf; selfo (100K x 48 f32) in hB.
    unsigned short* tmpn = nbuf;

    // CSR build (bucketed, L2-local scatters)
    k_hist<<<NB1, 256, 0, stream>>>(dst, histG, E);
    k_scanB<<<1, 1024, 0, stream>>>(histG);
    k_place<<<NB1, 256, 0, stream>>>(src, dst, histG, ebuf, E);
    k_csr<<<NBUCK, 256, 0, stream>>>(ebuf, histG, rp, col, invd, N, E);

    // dtype prep
    k_cvt<<<(N * 128 / 8 + 255) / 256, 256, 0, stream>>>(x, xb, N * 128 / 8);
    k_prepw<<<(5 * 4096 + 255) / 256, 256, 0, stream>>>(w_self, w_neigh, wp);
    k_prepwo<<<6, 256, 0, stream>>>(wso, wno, wS, wN, bo, bo48);

    const int aggBlocks = (N * 64 + 255) / 256;   // 25000
    const int gemmBlocks = (N + 63) / 64;         // 1563

    // layer 0 (no relu): agg(xb)->nbuf, gemm -> hA
    k_agg<<<aggBlocks, 256, 0, stream>>>(xb, rp, col, invd, nbuf, N);
    gemm128<<<gemmBlocks, 256, 0, stream>>>(xb, nbuf, wp, b, hA, N, 0);

    unsigned short* cur = hA;
    unsigned short* oth = hB;
    for (int lyr = 1; lyr < 5; ++lyr) {
        k_agg<<<aggBlocks, 256, 0, stream>>>(cur, rp, col, invd, nbuf, N);
        gemm128<<<gemmBlocks, 256, 0, stream>>>(cur, nbuf, wp + (size_t)lyr * 32768,
                                                b + (size_t)lyr * 128, oth, N, 1);
        unsigned short* t = cur; cur = oth; oth = t;
    }
    // after L0..L4: cur == hA, oth == hB

    // final layer: dense transforms first, then 128B-row aggregation
    float* selfo = (float*)hB;
    gemm_fin<<<gemmBlocks, 256, 0, stream>>>(cur, wS, wN, bo48, tmpn, selfo, N);
    k_agg_fin<<<aggBlocks, 256, 0, stream>>>(tmpn, selfo, rp, col, invd, out, N);
}

// Round 13
// 537.070 us; speedup vs baseline: 1.1016x; 1.0256x over previous
//
#include <hip/hip_runtime.h>

typedef float f4 __attribute__((ext_vector_type(4)));
typedef float f32x4 __attribute__((ext_vector_type(4)));
typedef float f2 __attribute__((ext_vector_type(2)));
typedef short s16x8 __attribute__((ext_vector_type(8)));
typedef int i4 __attribute__((ext_vector_type(4)));

#define N_NODES 100000
#define NBUCK 196   // ceil(100000/512)
#define NB1 256     // blocks in hist/place passes
#define GEMM_PERSIST 512   // 2 blocks/CU

__device__ inline unsigned short f2bf(float f) {
    unsigned int u = __builtin_bit_cast(unsigned int, f);
    u += 0x7FFFu + ((u >> 16) & 1u);
    return (unsigned short)(u >> 16);
}
__device__ inline float bflo(unsigned int v) { return __builtin_bit_cast(float, v << 16); }
__device__ inline float bfhi(unsigned int v) { return __builtin_bit_cast(float, v & 0xFFFF0000u); }

// async global->LDS, 16B per lane; LDS dest is wave-uniform base + lane*16
#define GLDS(gp, lp)                                                            \
    __builtin_amdgcn_global_load_lds(                                           \
        (const __attribute__((address_space(1))) void*)(gp),                    \
        (__attribute__((address_space(3))) void*)(lp), 16, 0, 0)

// accumulate 4 dwords (8 bf16) into 4 f2 accumulators
__device__ inline void acc8(f2& a0, f2& a1, f2& a2, f2& a3, i4 u) {
    f2 t0 = {bflo((unsigned int)u[0]), bfhi((unsigned int)u[0])};
    f2 t1 = {bflo((unsigned int)u[1]), bfhi((unsigned int)u[1])};
    f2 t2 = {bflo((unsigned int)u[2]), bfhi((unsigned int)u[2])};
    f2 t3 = {bflo((unsigned int)u[3]), bfhi((unsigned int)u[3])};
    a0 += t0; a1 += t1; a2 += t2; a3 += t3;
}

// ---------------- bucketed CSR build ----------------
// bucket = dst >> 9 (512 nodes per bucket); edge packed as src | (dst&511)<<17

__global__ __launch_bounds__(256) void k_hist(const int* __restrict__ dst,
                                              int* __restrict__ histG, int E) {
    __shared__ int h[NBUCK];
    int tid = threadIdx.x;
    for (int i = tid; i < NBUCK; i += 256) h[i] = 0;
    __syncthreads();
    int chunk = (E + NB1 - 1) / NB1;
    int s = blockIdx.x * chunk, eN = min(E, s + chunk);
    for (int i = s + tid; i < eN; i += 256) atomicAdd(&h[dst[i] >> 9], 1);
    __syncthreads();
    for (int i = tid; i < NBUCK; i += 256) histG[i * NB1 + blockIdx.x] = h[i];
}

__global__ __launch_bounds__(1024) void k_scanB(int* __restrict__ histG) {
    __shared__ int ps[1024];
    int t = threadIdx.x;
    int base = t * 49;
    int vals[49];
    int sum = 0;
#pragma unroll
    for (int i = 0; i < 49; ++i) { vals[i] = histG[base + i]; sum += vals[i]; }
    ps[t] = sum;
    __syncthreads();
    for (int off = 1; off < 1024; off <<= 1) {
        int v = (t >= off) ? ps[t - off] : 0;
        __syncthreads();
        ps[t] += v;
        __syncthreads();
    }
    int run = ps[t] - sum;
#pragma unroll
    for (int i = 0; i < 49; ++i) { int v = vals[i]; histG[base + i] = run; run += v; }
}

__global__ __launch_bounds__(256) void k_place(const int* __restrict__ src,
                                               const int* __restrict__ dst,
                                               const int* __restrict__ histG,
                                               unsigned int* __restrict__ ebuf, int E) {
    __shared__ int cur[NBUCK];
    int tid = threadIdx.x;
    for (int i = tid; i < NBUCK; i += 256) cur[i] = histG[i * NB1 + blockIdx.x];
    __syncthreads();
    int chunk = (E + NB1 - 1) / NB1;
    int s = blockIdx.x * chunk, eN = min(E, s + chunk);
    for (int i = s + tid; i < eN; i += 256) {
        int d = dst[i];
        int b = d >> 9;
        int pos = atomicAdd(&cur[b], 1);
        ebuf[pos] = (unsigned int)src[i] | ((unsigned int)(d & 511) << 17);
    }
}

// one block per bucket: LDS degree count + scan, then L2-local col scatter.
// col is stored as BYTE offsets (src*256) for the bf16 row gather.
__global__ __launch_bounds__(256) void k_csr(const unsigned int* __restrict__ ebuf,
                                             const int* __restrict__ histG,
                                             int* __restrict__ rp, int* __restrict__ col,
                                             float* __restrict__ invd, int N, int E) {
    __shared__ int ldeg[512];
    __shared__ int lbase[512];
    int b = blockIdx.x, tid = threadIdx.x;
    int base = histG[b * NB1];
    int endB = (b == NBUCK - 1) ? E : histG[(b + 1) * NB1];
    int cnt = endB - base;
    int n0 = b << 9;

    ldeg[tid] = 0;
    ldeg[tid + 256] = 0;
    __syncthreads();
    for (int i = tid; i < cnt; i += 256) atomicAdd(&ldeg[ebuf[base + i] >> 17], 1);
    __syncthreads();

    int a0 = ldeg[tid], a1 = ldeg[tid + 256];
    lbase[tid] = a0;
    lbase[tid + 256] = a1;
    __syncthreads();
    for (int off = 1; off < 512; off <<= 1) {
        int v0 = (tid >= off) ? lbase[tid - off] : 0;
        int v1 = (tid + 256 >= off) ? lbase[tid + 256 - off] : 0;
        __syncthreads();
        lbase[tid] += v0;
        lbase[tid + 256] += v1;
        __syncthreads();
    }
    int e0 = lbase[tid] - a0, e1 = lbase[tid + 256] - a1;
    __syncthreads();
    lbase[tid] = e0;
    lbase[tid + 256] = e1;
    ldeg[tid] = 0;
    ldeg[tid + 256] = 0;
    __syncthreads();

    for (int i = tid; i < cnt; i += 256) {
        unsigned int p = ebuf[base + i];
        int dl = p >> 17;
        int pos = base + lbase[dl] + atomicAdd(&ldeg[dl], 1);
        col[pos] = (int)(p & 0x1FFFFu) << 8;   // byte offset into 256B bf16 rows
    }

    int g0 = n0 + tid, g1 = n0 + tid + 256;
    if (g0 < N) { rp[g0] = base + e0; invd[g0] = 1.0f / fmaxf((float)a0, 1.0f); }
    if (g1 < N) { rp[g1] = base + e1; invd[g1] = 1.0f / fmaxf((float)a1, 1.0f); }
    if (b == NBUCK - 1 && tid == 0) rp[N] = E;
    if (b == NBUCK - 1 && tid < 32) col[E + tid] = 0;   // slack for tail over-read
}

// ---------------- prep: f32 -> bf16 conversions / weight packing ----------------

__global__ void k_cvt(const float* __restrict__ x, unsigned short* __restrict__ xb, int n8) {
    int t = blockIdx.x * 256 + threadIdx.x;
    if (t >= n8) return;
    f4 a = *(const f4*)&x[(size_t)t * 8];
    f4 b = *(const f4*)&x[(size_t)t * 8 + 4];
    s16x8 p;
    p[0] = (short)f2bf(a[0]); p[1] = (short)f2bf(a[1]);
    p[2] = (short)f2bf(a[2]); p[3] = (short)f2bf(a[3]);
    p[4] = (short)f2bf(b[0]); p[5] = (short)f2bf(b[1]);
    p[6] = (short)f2bf(b[2]); p[7] = (short)f2bf(b[3]);
    *(s16x8*)&xb[(size_t)t * 8] = p;
}

// merged weight packing:
//  t < 5*4096          : wp[layer][ks(8)][nfg(8)][lane(64)][8]  (k<128 -> ws else wn)
//  else (q = t-20480)  : q<48 -> bo48; q<1536 -> wS/wN[ks(4)][nf(3)][lane(64)][8]
__global__ void k_prep(const float* __restrict__ ws, const float* __restrict__ wn,
                       unsigned short* __restrict__ wp,
                       const float* __restrict__ wso, const float* __restrict__ wno,
                       unsigned short* __restrict__ wS, unsigned short* __restrict__ wN,
                       const float* __restrict__ bo, float* __restrict__ bo48) {
    int t = blockIdx.x * 256 + threadIdx.x;
    if (t < 5 * 4096) {
        int l = t & 63, nfg = (t >> 6) & 7, ks = (t >> 9) & 7, lyr = t >> 12;
        int n = nfg * 16 + (l & 15);
        s16x8 p;
#pragma unroll
        for (int j = 0; j < 8; ++j) {
            int k = ks * 32 + (l >> 4) * 8 + j;
            float v = (k < 128) ? ws[((size_t)lyr * 128 + k) * 128 + n]
                                : wn[((size_t)lyr * 128 + (k - 128)) * 128 + n];
            p[j] = (short)f2bf(v);
        }
        *(s16x8*)&wp[(size_t)t * 8] = p;
        return;
    }
    int q = t - 5 * 4096;
    if (q < 48) bo48[q] = (q < 47) ? bo[q] : 0.f;
    if (q >= 2 * 768) return;
    int tbl = q / 768, r = q % 768;
    int ks = r / 192, nf = (r / 64) % 3, l = r & 63;
    int n = nf * 16 + (l & 15);
    const float* W = tbl ? wno : wso;
    unsigned short* dstp = tbl ? wN : wS;
    s16x8 p;
#pragma unroll
    for (int j = 0; j < 8; ++j) {
        int k = ks * 32 + (l >> 4) * 8 + j;
        float v = (n < 47) ? W[(size_t)k * 47 + n] : 0.f;
        p[j] = (short)f2bf(v);
    }
    *(s16x8*)&dstp[(size_t)r * 8] = p;
}

// ---------------- mean aggregation, dwordx4 gather (R10-proven form) -----------
// Lane i serves edge e + (i>>4), bytes (i&15)*16 of that 256B row.

__global__ __launch_bounds__(256) void k_agg(const unsigned short* __restrict__ h,
                                             const int* __restrict__ rp,
                                             const int* __restrict__ col,
                                             const float* __restrict__ invd,
                                             unsigned short* __restrict__ out, int n) {
    int gw = (blockIdx.x * 256 + threadIdx.x) >> 6;
    int lane = threadIdx.x & 63;
    if (gw >= n) return;
    const char* hb = (const char*)h;
    const int sub = lane >> 4;          // edge slot within quad
    const int lb = (lane & 15) * 16;    // byte chunk within 256B row
    int beg = rp[gw], end = rp[gw + 1];
    f2 a0 = {0.f, 0.f}, a1 = {0.f, 0.f}, a2 = {0.f, 0.f}, a3 = {0.f, 0.f};
    int e = beg;
    for (; e + 8 <= end; e += 8) {
        unsigned int c0 = (unsigned int)col[e + sub];
        unsigned int c1 = (unsigned int)col[e + 4 + sub];
        i4 u, v;
        __builtin_memcpy(&u, hb + c0 + lb, 16);
        __builtin_memcpy(&v, hb + c1 + lb, 16);
        acc8(a0, a1, a2, a3, u);
        acc8(a0, a1, a2, a3, v);
    }
    if (e < end) {
        // masked tail (1..7 edges); col slack (>=32 zeros) keeps reads in-bounds
        unsigned int c0 = (unsigned int)col[e + sub];
        unsigned int c1 = (unsigned int)col[e + 4 + sub];
        i4 u, v;
        __builtin_memcpy(&u, hb + c0 + lb, 16);
        __builtin_memcpy(&v, hb + c1 + lb, 16);
        if (e + sub < end) acc8(a0, a1, a2, a3, u);
        if (e + 4 + sub < end) acc8(a0, a1, a2, a3, v);
    }
    // reduce the 4 edge-slots: lanes {i, i^16, i^32, i^48} hold the same chunk
#pragma unroll
    for (int off = 16; off <= 32; off <<= 1) {
        a0[0] += __shfl_xor(a0[0], off); a0[1] += __shfl_xor(a0[1], off);
        a1[0] += __shfl_xor(a1[0], off); a1[1] += __shfl_xor(a1[1], off);
        a2[0] += __shfl_xor(a2[0], off); a2[1] += __shfl_xor(a2[1], off);
        a3[0] += __shfl_xor(a3[0], off); a3[1] += __shfl_xor(a3[1], off);
    }
    if (lane < 16) {
        float iv = invd[gw];
        i4 r;
        r[0] = (int)((unsigned int)f2bf(a0[0] * iv) | ((unsigned int)f2bf(a0[1] * iv) << 16));
        r[1] = (int)((unsigned int)f2bf(a1[0] * iv) | ((unsigned int)f2bf(a1[1] * iv) << 16));
        r[2] = (int)((unsigned int)f2bf(a2[0] * iv) | ((unsigned int)f2bf(a2[1] * iv) << 16));
        r[3] = (int)((unsigned int)f2bf(a3[0] * iv) | ((unsigned int)f2bf(a3[1] * iv) << 16));
        *(i4*)((char*)out + (size_t)gw * 256 + lb) = r;
    }
}

// ---------------- persistent double-buffered dual MFMA GEMM --------------------
// out = relu?(h@Ws + nb@Wn + b). 64-row tiles; each block processes tiles
// blockIdx.x, +512, ... with 2-phase pipeline: stage(t+1) overlaps compute(t).
// LDS 2 x 32KB; weights + bias preloaded to registers once per block.

__global__ __launch_bounds__(256, 2) void gemm128(const unsigned short* __restrict__ h,
                                                  const unsigned short* __restrict__ nb,
                                                  const unsigned short* __restrict__ wl,
                                                  const float* __restrict__ bias,
                                                  unsigned short* __restrict__ out,
                                                  int M, int relu, int nt) {
    __shared__ s16x8 afr[2][2048];
    const int tid = threadIdx.x;
    const int l = tid & 63, w = tid >> 6;
    const int cg = (w * 4 + (l >> 4)) * 8;
    const s16x8* wf = (const s16x8*)wl;

    // preload weight fragments (reused across tiles)
    s16x8 bwr[8][2];
#pragma unroll
    for (int ks = 0; ks < 8; ++ks)
#pragma unroll
        for (int nf = 0; nf < 2; ++nf) bwr[ks][nf] = wf[(ks * 8 + w * 2 + nf) * 64 + l];
    f4 bv[2];
#pragma unroll
    for (int nf = 0; nf < 2; ++nf)
        bv[nf] = *(const f4*)&bias[w * 32 + nf * 16 + ((l >> 4) << 2)];

    int t = blockIdx.x;
    if (t >= nt) return;

    // prologue: stage tile t into buffer 0
    {
        const int r0 = t * 64;
#pragma unroll
        for (int i = 0; i < 4; ++i) {
            int r = r0 + i * 16 + (l & 15);
            if (r >= M) r = M - 1;
            GLDS(h + (size_t)r * 128 + cg, &afr[0][(w * 4 + i) * 64]);
            GLDS(nb + (size_t)r * 128 + cg, &afr[0][(16 + w * 4 + i) * 64]);
        }
    }
    asm volatile("s_waitcnt vmcnt(0)");
    __syncthreads();

    int cur = 0;
    for (; t < nt; t += GEMM_PERSIST) {
        // stage next tile into the other buffer (overlaps compute below)
        int tn = t + GEMM_PERSIST;
        if (tn < nt) {
            const int r0n = tn * 64;
#pragma unroll
            for (int i = 0; i < 4; ++i) {
                int r = r0n + i * 16 + (l & 15);
                if (r >= M) r = M - 1;
                GLDS(h + (size_t)r * 128 + cg, &afr[cur ^ 1][(w * 4 + i) * 64]);
                GLDS(nb + (size_t)r * 128 + cg, &afr[cur ^ 1][(16 + w * 4 + i) * 64]);
            }
        }

        // compute tile t from afr[cur]
        const int r0 = t * 64;
        f32x4 acc[4][2];
#pragma unroll
        for (int i = 0; i < 4; ++i)
#pragma unroll
            for (int j = 0; j < 2; ++j) acc[i][j] = (f32x4)0.f;

#pragma unroll
        for (int ks = 0; ks < 8; ++ks) {
            const int base = (ks < 4) ? (ks * 4) : (16 + (ks - 4) * 4);
            s16x8 ha[4];
#pragma unroll
            for (int mf = 0; mf < 4; ++mf) ha[mf] = afr[cur][(base + mf) * 64 + l];
#pragma unroll
            for (int mf = 0; mf < 4; ++mf)
#pragma unroll
                for (int nf = 0; nf < 2; ++nf)
                    acc[mf][nf] = __builtin_amdgcn_mfma_f32_16x16x32_bf16(
                        bwr[ks][nf], ha[mf], acc[mf][nf], 0, 0, 0);
        }

#pragma unroll
        for (int mf = 0; mf < 4; ++mf) {
            int row = r0 + mf * 16 + (l & 15);
            if (row >= M) continue;
#pragma unroll
            for (int nf = 0; nf < 2; ++nf) {
                int ncol = w * 32 + nf * 16 + ((l >> 4) << 2);
                f32x4 a = acc[mf][nf];
                float v0 = a[0] + bv[nf][0], v1 = a[1] + bv[nf][1];
                float v2 = a[2] + bv[nf][2], v3 = a[3] + bv[nf][3];
                if (relu) {
                    v0 = fmaxf(v0, 0.f); v1 = fmaxf(v1, 0.f);
                    v2 = fmaxf(v2, 0.f); v3 = fmaxf(v3, 0.f);
                }
                uint2 p;
                p.x = (unsigned int)f2bf(v0) | ((unsigned int)f2bf(v1) << 16);
                p.y = (unsigned int)f2bf(v2) | ((unsigned int)f2bf(v3) << 16);
                *(uint2*)(out + (size_t)row * 128 + ncol) = p;
            }
        }

        asm volatile("s_waitcnt vmcnt(0)");
        __syncthreads();
        cur ^= 1;
    }
}

// ---------------- final layer, dense part (LDS-staged h) -----------------------
// tmpn = h@wno (bf16), selfo = h@wso + bo (f32). 64-row tile, 16 KB LDS.

__global__ __launch_bounds__(256, 4) void gemm_fin(const unsigned short* __restrict__ h,
                                                   const unsigned short* __restrict__ wS,
                                                   const unsigned short* __restrict__ wN,
                                                   const float* __restrict__ bo48,
                                                   unsigned short* __restrict__ tmpn,
                                                   float* __restrict__ selfo, int M) {
    __shared__ s16x8 afr[1024];  // 16 slots x 64 lanes : 16 KB
    const int tid = threadIdx.x;
    const int l = tid & 63, wv = tid >> 6;
    const int r0 = blockIdx.x * 64;
    const int cg = (wv * 4 + (l >> 4)) * 8;

#pragma unroll
    for (int i = 0; i < 4; ++i) {
        int r = r0 + i * 16 + (l & 15);
        if (r >= M) r = M - 1;
        GLDS(h + (size_t)r * 128 + cg, &afr[(wv * 4 + i) * 64]);
    }
    asm volatile("s_waitcnt vmcnt(0)");
    __syncthreads();

    const int mh = wv >> 1, sel = wv & 1;
    const s16x8* wf = (const s16x8*)(sel ? wN : wS);

    f32x4 acc[2][3];
#pragma unroll
    for (int i = 0; i < 2; ++i)
#pragma unroll
        for (int j = 0; j < 3; ++j) acc[i][j] = (f32x4)0.f;

#pragma unroll
    for (int ks = 0; ks < 4; ++ks) {
        s16x8 ha[2], bw[3];
#pragma unroll
        for (int mf = 0; mf < 2; ++mf) ha[mf] = afr[(ks * 4 + mh * 2 + mf) * 64 + l];
#pragma unroll
        for (int nf = 0; nf < 3; ++nf) bw[nf] = wf[(ks * 3 + nf) * 64 + l];
#pragma unroll
        for (int mf = 0; mf < 2; ++mf)
#pragma unroll
            for (int nf = 0; nf < 3; ++nf)
                acc[mf][nf] = __builtin_amdgcn_mfma_f32_16x16x32_bf16(bw[nf], ha[mf],
                                                                      acc[mf][nf], 0, 0, 0);
    }

#pragma unroll
    for (int mf = 0; mf < 2; ++mf) {
        int row = r0 + mh * 32 + mf * 16 + (l & 15);
        if (row >= M) continue;
#pragma unroll
        for (int nf = 0; nf < 3; ++nf) {
            int ncol = nf * 16 + ((l >> 4) << 2);
            f32x4 a = acc[mf][nf];
            if (sel == 0) {
                f4 bv = *(const f4*)&bo48[ncol];
                f4 o;
                o[0] = a[0] + bv[0]; o[1] = a[1] + bv[1];
                o[2] = a[2] + bv[2]; o[3] = a[3] + bv[3];
                *(f4*)&selfo[(size_t)row * 48 + ncol] = o;
            } else {
                uint2 p;
                p.x = (unsigned int)f2bf(a[0]) | ((unsigned int)f2bf(a[1]) << 16);
                p.y = (unsigned int)f2bf(a[2]) | ((unsigned int)f2bf(a[3]) << 16);
                *(uint2*)(tmpn + (size_t)row * 64 + ncol) = p;
            }
        }
    }
}

// ---------------- final aggregation over 128B rows (R9-proven form) ------------
// One wave per node; 32 lanes per edge -> 2 rows per gather instruction.

__global__ __launch_bounds__(256) void k_agg_fin(const unsigned short* __restrict__ z,
                                                 const float* __restrict__ selfo,
                                                 const int* __restrict__ rp,
                                                 const int* __restrict__ col,
                                                 const float* __restrict__ invd,
                                                 float* __restrict__ out, int n) {
    int gw = (blockIdx.x * 256 + threadIdx.x) >> 6;
    int lane = threadIdx.x & 63;
    if (gw >= n) return;
    const char* zb = (const char*)z;
    const int hhalf = lane >> 5;        // 0: even edges, 1: odd edges
    const int lb = (lane & 31) * 4;     // byte within 128B row
    int beg = rp[gw], end = rp[gw + 1];
    f2 acc = {0.f, 0.f};
    int e = beg;
    for (; e + 8 <= end; e += 8) {
        unsigned int u[4];
#pragma unroll
        for (int j = 0; j < 4; ++j) {
            unsigned int c = (unsigned int)col[e + 2 * j + hhalf];  // src*256
            u[j] = *(const unsigned int*)(zb + (c >> 1) + lb);
        }
#pragma unroll
        for (int j = 0; j < 4; ++j) { f2 v = {bflo(u[j]), bfhi(u[j])}; acc += v; }
    }
    if (e < end) {
        int rem = end - e;  // 1..7; col slack (>=32 zeros) makes reads safe
        unsigned int u[4];
#pragma unroll
        for (int j = 0; j < 4; ++j) {
            unsigned int c = (unsigned int)col[e + 2 * j + hhalf];
            u[j] = *(const unsigned int*)(zb + (c >> 1) + lb);
        }
#pragma unroll
        for (int j = 0; j < 4; ++j) {
            if (2 * j + hhalf < rem) { f2 v = {bflo(u[j]), bfhi(u[j])}; acc += v; }
        }
    }
    // combine the two half-wave partial sums (lane l <-> l+32 hold same cols)
    f2 tot;
    tot[0] = acc[0] + __shfl_xor(acc[0], 32);
    tot[1] = acc[1] + __shfl_xor(acc[1], 32);
    float iv = invd[gw];
    if (lane < 24) {
        int c0 = lane * 2;   // cols c0, c0+1 (real cols are 0..46)
        f2 s = *(const f2*)&selfo[(size_t)gw * 48 + c0];
        out[(size_t)gw * 47 + c0] = s[0] + tot[0] * iv;
        if (c0 + 1 < 47) out[(size_t)gw * 47 + c0 + 1] = s[1] + tot[1] * iv;
    }
}

// ---------------- launch ----------------

static inline char* alignp(char* p) {
    return (char*)(((size_t)p + 255) & ~(size_t)255);
}

extern "C" void kernel_launch(void* const* d_in, const int* in_sizes, int n_in,
                              void* d_out, int out_size, void* d_ws, size_t ws_size,
                              hipStream_t stream) {
    const float* x = (const float*)d_in[0];
    const int* src = (const int*)d_in[1];
    const int* dst = (const int*)d_in[2];
    const float* w_self = (const float*)d_in[3];
    const float* w_neigh = (const float*)d_in[4];
    const float* b = (const float*)d_in[5];
    const float* wso = (const float*)d_in[6];
    const float* wno = (const float*)d_in[7];
    const float* bo = (const float*)d_in[8];
    float* out = (float*)d_out;

    const int N = N_NODES;
    const int E = in_sizes[1];

    char* w = (char*)d_ws;
    unsigned short* xb = (unsigned short*)w;   w = alignp(w + (size_t)N * 128 * 2);
    unsigned short* hA = (unsigned short*)w;   w = alignp(w + (size_t)N * 128 * 2);
    unsigned short* hB = (unsigned short*)w;   w = alignp(w + (size_t)N * 128 * 2);
    unsigned short* nbuf = (unsigned short*)w; w = alignp(w + (size_t)N * 128 * 2);
    unsigned short* wp = (unsigned short*)w;   w = alignp(w + (size_t)5 * 32768 * 2);
    unsigned short* wS = (unsigned short*)w;   w = alignp(w + (size_t)768 * 8 * 2);
    unsigned short* wN = (unsigned short*)w;   w = alignp(w + (size_t)768 * 8 * 2);
    float* bo48 = (float*)w; w = alignp(w + 48 * 4);
    int* rp = (int*)w;       w = alignp(w + (size_t)(N + 4) * 4);
    int* col = (int*)w;      w = alignp(w + (size_t)(E + 32) * 4);
    int* histG = (int*)w;    w = alignp(w + (size_t)NBUCK * NB1 * 4);
    float* invd = (float*)w; w = alignp(w + (size_t)N * 4);

    // Aliases (lifetimes disjoint):
    // ebuf (packed edges) lives in hB: hB first written at layer-1 GEMM output.
    unsigned int* ebuf = (unsigned int*)hB;
    // final layer: tmpn (100K x 64 bf16) in nbuf; selfo (100K x 48 f32) in hB.
    unsigned short* tmpn = nbuf;

    // CSR build (bucketed, L2-local scatters)
    k_hist<<<NB1, 256, 0, stream>>>(dst, histG, E);
    k_scanB<<<1, 1024, 0, stream>>>(histG);
    k_place<<<NB1, 256, 0, stream>>>(src, dst, histG, ebuf, E);
    k_csr<<<NBUCK, 256, 0, stream>>>(ebuf, histG, rp, col, invd, N, E);

    // dtype prep
    k_cvt<<<(N * 128 / 8 + 255) / 256, 256, 0, stream>>>(x, xb, N * 128 / 8);
    k_prep<<<(5 * 4096 + 1536 + 255) / 256, 256, 0, stream>>>(
        w_self, w_neigh, wp, wso, wno, wS, wN, bo, bo48);

    const int aggBlocks = (N * 64 + 255) / 256;   // 25000
    const int nt = (N + 63) / 64;                 // 1563 tiles
    const int gemmGrid = (nt < GEMM_PERSIST) ? nt : GEMM_PERSIST;

    // layer 0 (no relu): agg(xb)->nbuf, gemm -> hA
    k_agg<<<aggBlocks, 256, 0, stream>>>(xb, rp, col, invd, nbuf, N);
    gemm128<<<gemmGrid, 256, 0, stream>>>(xb, nbuf, wp, b, hA, N, 0, nt);

    unsigned short* cur = hA;
    unsigned short* oth = hB;
    for (int lyr = 1; lyr < 5; ++lyr) {
        k_agg<<<aggBlocks, 256, 0, stream>>>(cur, rp, col, invd, nbuf, N);
        gemm128<<<gemmGrid, 256, 0, stream>>>(cur, nbuf, wp + (size_t)lyr * 32768,
                                              b + (size_t)lyr * 128, oth, N, 1, nt);
        unsigned short* t = cur; cur = oth; oth = t;
    }
    // after L0..L4: cur == hA, oth == hB

    // final layer: dense transforms first, then 128B-row aggregation
    float* selfo = (float*)hB;
    gemm_fin<<<nt, 256, 0, stream>>>(cur, wS, wN, bo48, tmpn, selfo, N);
    k_agg_fin<<<aggBlocks, 256, 0, stream>>>(tmpn, selfo, rp, col, invd, out, N);
}